// Round 8
// baseline (1129.553 us; speedup 1.0000x reference)
//
#include <hip/hip_runtime.h>

// DA-RNN fused — R16: 3-barrier decoder via phase re-fusion.
//  * R15 post-mortem: both predictions hit (conflicts 29.9M->3.7M, 1233->1126).
//    Remaining stall ~44% = barrier drains + dep chains.
//  * Key observation: R15b's y-injection made S6 read ONLY prev-step state
//    (shp/scp) — same inputs as S0. So: P1={S0+S6} | bar | P2={S2} | bar |
//    P3={S3+S7} | bar. 4 -> 3 barriers/step (-100 block barriers), and P1
//    fuses the two largest dot streams (384 dot2h) into one ILP-rich phase.
//  * Math is bit-identical to R15 (pure phase reorder): absmax must match.
//  * Everything else identical to R15 (512 thr, BPB=4, packed-fp16 S2,
//    rotated S0, slim S3, y-injection S7).

typedef unsigned int   u32;
typedef unsigned short u16;

#define T_  100
#define C_  32
#define NT  512
#define BPB 4
#define TS  132
#define QS  (T_ * NT)

typedef __attribute__((ext_vector_type(2))) __fp16 h16x2;

#if __has_builtin(__builtin_amdgcn_fdot2)
#define HAVE_FDOT2 1
#else
#define HAVE_FDOT2 0
#endif

__device__ __forceinline__ u32 pkh2(float a, float b) {
#if __has_builtin(__builtin_amdgcn_cvt_pkrtz)
  h16x2 p = __builtin_amdgcn_cvt_pkrtz(a, b);
  return __builtin_bit_cast(u32, p);
#else
  union { __fp16 h[2]; u32 u; } v;
  v.h[0] = (__fp16)a; v.h[1] = (__fp16)b;
  return v.u;
#endif
}
__device__ __forceinline__ void unph(u32 p, float& lo, float& hi) {
  union { u32 u; __fp16 h[2]; } v; v.u = p;
  lo = (float)v.h[0]; hi = (float)v.h[1];
}
__device__ __forceinline__ u16 f2h(float f) {
  union { __fp16 h; u16 u; } v; v.h = (__fp16)f; return v.u;
}
__device__ __forceinline__ float h2f(u16 u) {
  union { u16 u; __fp16 h; } v; v.u = u; return (float)v.h;
}
__device__ __forceinline__ float dot2h(u32 w, u32 x, float acc) {
#if HAVE_FDOT2
  return __builtin_amdgcn_fdot2(__builtin_bit_cast(h16x2, w),
                                __builtin_bit_cast(h16x2, x),
                                acc, false);
#else
  float a, b, c, d;
  unph(w, a, b); unph(x, c, d);
  return fmaf(a, c, fmaf(b, d, acc));
#endif
}

#if __has_builtin(__builtin_amdgcn_rcpf)
__device__ __forceinline__ float rcpf_(float x){ return __builtin_amdgcn_rcpf(x); }
#else
__device__ __forceinline__ float rcpf_(float x){ return 1.0f / x; }
#endif
__device__ __forceinline__ float sigm(float x){ return rcpf_(1.0f + __expf(-x)); }
__device__ __forceinline__ float tanh_(float x){
  return 1.0f - 2.0f * rcpf_(1.0f + __expf(2.0f * x));
}
__device__ __forceinline__ float ptanh(float x){
  x = fminf(1.0f, fmaxf(-1.0f, x));
  float x2 = x * x;
  float p  = fmaf(x2, 0.1333333f, -0.3333333f);
  return x * fmaf(x2, p, 1.0f);
}
// packed-fp16 tanh approx of (e+u), both packed half2 as u32
__device__ __forceinline__ u32 tanhpk(u32 eu, u32 uu) {
  h16x2 x = __builtin_bit_cast(h16x2, eu) + __builtin_bit_cast(h16x2, uu);
  const h16x2 one  = {(__fp16)1.0f,  (__fp16)1.0f};
#if __has_builtin(__builtin_elementwise_max) && __has_builtin(__builtin_elementwise_min)
  const h16x2 mone = {(__fp16)-1.0f, (__fp16)-1.0f};
  x = __builtin_elementwise_min(one, __builtin_elementwise_max(x, mone));
#else
  {
    float lo, hi; unph(__builtin_bit_cast(u32, x), lo, hi);
    x = (h16x2){(__fp16)fminf(1.f, fmaxf(-1.f, lo)),
                (__fp16)fminf(1.f, fmaxf(-1.f, hi))};
  }
#endif
  h16x2 x2 = x * x;
  const h16x2 c1 = {(__fp16)0.1333333f,  (__fp16)0.1333333f};
  const h16x2 c0 = {(__fp16)-0.3333333f, (__fp16)-0.3333333f};
  h16x2 r = x * (x2 * (x2 * c1 + c0) + one);
  return __builtin_bit_cast(u32, r);
}
__device__ __forceinline__ float wsum(float v){
  #pragma unroll
  for (int o = 32; o; o >>= 1) v += __shfl_xor(v, o, 64);
  return v;
}

// ============================ fast kernel (4 batches/block) =================
__global__ void __launch_bounds__(NT)
darnn4(const float* __restrict__ X,
       const float* __restrict__ eWih, const float* __restrict__ eWhh,
       const float* __restrict__ ebih, const float* __restrict__ ebhh,
       const float* __restrict__ eAw,  const float* __restrict__ eAb,
       const float* __restrict__ dW1,  const float* __restrict__ db1,
       const float* __restrict__ dW2,  const float* __restrict__ db2,
       const float* __restrict__ dWih, const float* __restrict__ dWhh,
       const float* __restrict__ dbih, const float* __restrict__ dbhh,
       const float* __restrict__ fcW,  const float* __restrict__ fcb,
       const float* __restrict__ fcfW, const float* __restrict__ fcfb,
       u16* __restrict__ qws,
       float* __restrict__ out)
{
  // LDS ~130.5 KB
  __shared__ __align__(16) u16   sE1[BPB][T_ * TS];  // x_tilde -> E1   105600
  __shared__ __align__(16) float sg[BPB][512];       //                  8192
  __shared__ __align__(16) float sh[BPB][128];       // h/d fp32         2048
  __shared__ __align__(16) float sc[BPB][128];       // c fp32           2048
  __shared__ __align__(16) u16   shp[BPB][128];      // h/d fp16         1024
  __shared__ __align__(16) u16   scp[BPB][128];      // c fp16           1024
  __shared__ __align__(16) float su[BPB][128];       // ctx              2048
  __shared__ __align__(16) float spart[BPB][512];    // partials         8192
  __shared__ __align__(16) float sye[BPB][128];      // ye -> beta       2048
  __shared__ __align__(16) u32   su2[BPB][64];       // packed u         1024
  __shared__ __align__(16) u32   sw2p[64];           // packed w2         256
  __shared__ float sred[16];

  const int tid  = threadIdx.x;
  const int lane = tid & 63;
  const int wv   = tid >> 6;     // 0..7
  const int hh   = tid & 127;
  const int q4   = tid >> 7;     // 0..3
  const int h4   = tid >> 2;     // 0..127 (S0 row)
  const int p4   = tid & 3;      // S0 column quarter
  const int b0   = blockIdx.x * BPB;

  (void)eAb; (void)db2;          // cancel under softmax shift-invariance

  if (tid < 64) sw2p[tid] = pkh2(dW2[2 * tid], dW2[2 * tid + 1]);

  // ---------- alpha (no max-sub; h/c terms cancel) + x_tilde ----------
  {
    const float* xp = X + (size_t)(b0 + q4) * 12800 + hh;
    float sval = 0.f;
    #pragma unroll 4
    for (int t = 0; t < T_; ++t) sval += xp[t * 128] * eAw[256 + t];
    float e = __expf(sval);
    float s = wsum(e);
    if (lane == 0) sred[wv] = s;
    __syncthreads();
    float al = e * rcpf_(sred[q4 * 2] + sred[q4 * 2 + 1]);
    #pragma unroll 4
    for (int t = 0; t < T_; ++t)
      sE1[q4][t * TS + hh] = f2h(al * xp[t * 128]);
    sh[q4][hh] = 0.f; sc[q4][hh] = 0.f; shp[q4][hh] = 0; scp[q4][hh] = 0;
  }
  __syncthreads();

  // ---------- Q GEMM: Q[b][t][r] = eWih[r,:]·x_tilde  (self-produced) ----
  {
    u32 wq[64];
    const float4* wi = (const float4*)(eWih + (size_t)tid * 128);
    #pragma unroll
    for (int i = 0; i < 32; ++i) {
      float4 v = wi[i];
      wq[2*i]   = pkh2(v.x, v.y);
      wq[2*i+1] = pkh2(v.z, v.w);
    }
    #pragma unroll 1
    for (int bg = 0; bg < BPB; ++bg) {
      u16* qb = qws + (size_t)(b0 + bg) * QS;
      #pragma unroll 1
      for (int t = 0; t < T_; ++t) {
        const uint2* xr = (const uint2*)(&sE1[bg][t * TS]);
        float a0 = 0.f, a1 = 0.f;
        #pragma unroll
        for (int k = 0; k < 16; ++k) {
          uint2 xv = xr[k];
          a0 = dot2h(wq[2*k],   xv.x, a0);
          a1 = dot2h(wq[2*k+1], xv.y, a1);
        }
        qb[t * NT + tid] = f2h(a0 + a1);
      }
    }
  }

  // ---------- encoder (2 barriers/step) ----------
  {
    u32 wpkH[64];
    const float4* wr = (const float4*)(eWhh + (size_t)tid * 128);
    #pragma unroll
    for (int i = 0; i < 32; ++i) {
      float4 v = wr[i];
      wpkH[2*i]   = pkh2(v.x, v.y);
      wpkH[2*i+1] = pkh2(v.z, v.w);
    }
    float biasg = ebih[tid] + ebhh[tid];

    u16 qc[BPB];
    #pragma unroll
    for (int bg = 0; bg < BPB; ++bg)
      qc[bg] = qws[(size_t)(b0 + bg) * QS + tid];

    for (int t = 0; t < T_; ++t) {
      u16 qn[BPB];
      #pragma unroll
      for (int bg = 0; bg < BPB; ++bg)
        qn[bg] = (t + 1 < T_) ? qws[(size_t)(b0 + bg) * QS + (t + 1) * NT + tid]
                              : (u16)0;
      #pragma unroll 1
      for (int bg = 0; bg < BPB; ++bg) {
        const uint4* hr = (const uint4*)(const u32*)shp[bg];
        float a0 = biasg + h2f(qc[bg]), a1 = 0.f, a2 = 0.f, a3 = 0.f;
        #pragma unroll
        for (int k = 0; k < 16; ++k) {
          uint4 hv = hr[k];
          a0 = dot2h(wpkH[4*k+0], hv.x, a0);
          a1 = dot2h(wpkH[4*k+1], hv.y, a1);
          a2 = dot2h(wpkH[4*k+2], hv.z, a2);
          a3 = dot2h(wpkH[4*k+3], hv.w, a3);
        }
        sg[bg][tid] = (a0 + a1) + (a2 + a3);
      }
      __syncthreads();
      {
        float gi = sigm(sg[q4][hh]);
        float gf = sigm(sg[q4][hh + 128]);
        float gg = tanh_(sg[q4][hh + 256]);
        float go = sigm(sg[q4][hh + 384]);
        float c  = gf * sc[q4][hh] + gi * gg;
        sc[q4][hh] = c;
        float h  = go * tanh_(c);
        sh[q4][hh] = h;
        u16 hb = f2h(h);
        shp[q4][hh] = hb;
        scp[q4][hh] = f2h(c);
        // Xe row t shares Q's slab (Q[t] already consumed; barrier-ordered)
        qws[(size_t)(b0 + q4) * QS + t * NT + hh] = hb;
      }
      __syncthreads();
      #pragma unroll
      for (int bg = 0; bg < BPB; ++bg) qc[bg] = qn[bg];
    }
  }

  // ---------- ye[t] = fcW · Xe[t]  ----------
  if (hh < T_) {
    #pragma unroll 1
    for (int bg = 0; bg < BPB; ++bg) {
      const uint2* xe = (const uint2*)(qws + (size_t)(b0 + bg) * QS
                                       + hh * NT + q4 * 32);
      const float* fw = fcW + q4 * 32;
      float a = 0.f;
      #pragma unroll
      for (int k = 0; k < 8; ++k) {
        uint2 xv = xe[k];
        float l0, l1, l2, l3;
        unph(xv.x, l0, l1); unph(xv.y, l2, l3);
        a += fw[4*k]*l0 + fw[4*k+1]*l1 + fw[4*k+2]*l2 + fw[4*k+3]*l3;
      }
      spart[bg][hh * 4 + q4] = a;
    }
  }
  __syncthreads();
  if (hh < T_) {
    float4 p = ((const float4*)spart[q4])[hh];
    sye[q4][hh] = (p.x + p.y) + (p.z + p.w);
  }
  __syncthreads();

  // ---------- E1[t][h] = dW1[h][256:384]·Xe[t] + db1[h] -> LDS ----------
  {
    u32 wtp[64];
    const float4* w4p = (const float4*)(dW1 + (size_t)hh * 384 + 256);
    #pragma unroll
    for (int i = 0; i < 32; ++i) {
      float4 v = w4p[i];
      wtp[2*i]   = pkh2(v.x, v.y);
      wtp[2*i+1] = pkh2(v.z, v.w);
    }
    float b1v = db1[hh];
    #pragma unroll 1
    for (int bg = 0; bg < BPB; ++bg) {
      #pragma unroll 1
      for (int i = 0; i < 25; ++i) {
        int t = q4 * 25 + i;
        const uint2* xe = (const uint2*)(qws + (size_t)(b0 + bg) * QS + t * NT);
        float a0 = 0.f, a1 = 0.f;
        #pragma unroll
        for (int k = 0; k < 16; ++k) {
          uint2 xv = xe[k];
          a0 = dot2h(wtp[2*k],   xv.x, a0);
          a1 = dot2h(wtp[2*k+1], xv.y, a1);
        }
        sE1[bg][t * TS + hh] = f2h(a0 + a1 + b1v);
      }
    }
  }

  // ---------- decoder weights ----------
  u32 wpkD[64];
  {
    const float4* wr = (const float4*)(dWhh + (size_t)tid * 128);
    #pragma unroll
    for (int i = 0; i < 32; ++i) {
      float4 v = wr[i];
      wpkD[2*i]   = pkh2(v.x, v.y);
      wpkD[2*i+1] = pkh2(v.z, v.w);
    }
  }
  // S0 weights, segment-rotated: wtpU[4*kk..] holds z-cols
  // [p4*64 + 8*k, +8) with k=(kk+2*p4)&7 -> reads hit disjoint banks.
  u32 wtpU[32];
  {
    const float4* wu = (const float4*)(dW1 + (size_t)h4 * 384 + p4 * 64);
    #pragma unroll
    for (int kk = 0; kk < 8; ++kk) {
      int k = (kk + 2 * p4) & 7;
      float4 v0 = wu[2*k], v1 = wu[2*k + 1];
      wtpU[4*kk+0] = pkh2(v0.x, v0.y);
      wtpU[4*kk+1] = pkh2(v0.z, v0.w);
      wtpU[4*kk+2] = pkh2(v1.x, v1.y);
      wtpU[4*kk+3] = pkh2(v1.z, v1.w);
    }
  }
  float biasD = dbih[tid] + dbhh[tid];
  // dWih rows for the S7 y-injection (thread covers gates hh, hh+128, ...)
  float wix = dWih[hh];
  float wiy = dWih[hh + 128];
  float wiz = dWih[hh + 256];
  float wiw = dWih[hh + 384];
  float fcbv  = fcb[0];
  sh[q4][hh] = 0.f; sc[q4][hh] = 0.f; shp[q4][hh] = 0; scp[q4][hh] = 0;
  __syncthreads();

  // ---------- decoder (3 barriers/step) ----------
  for (int step = 0; step < T_; ++step) {
    // P1a (S0): u[h4] partial over z-cols p4*64..+64, rotated segment order;
    //           butterfly reduce in-wave; write packed su2[bg][h4>>1]
    #pragma unroll 1
    for (int bg = 0; bg < BPB; ++bg) {
      const u32* bs = (p4 < 2) ? (const u32*)shp[bg] + (p4 & 1) * 32
                               : (const u32*)scp[bg] + (p4 & 1) * 32;
      const uint4* vp = (const uint4*)bs;
      float a0 = 0.f, a1 = 0.f;
      #pragma unroll
      for (int kk = 0; kk < 8; ++kk) {
        int k = (kk + 2 * p4) & 7;
        uint4 v = vp[k];
        a0 = dot2h(wtpU[4*kk+0], v.x, a0);
        a1 = dot2h(wtpU[4*kk+1], v.y, a1);
        a0 = dot2h(wtpU[4*kk+2], v.z, a0);
        a1 = dot2h(wtpU[4*kk+3], v.w, a1);
      }
      float a = a0 + a1;
      a += __shfl_xor(a, 1, 64);
      a += __shfl_xor(a, 2, 64);          // all 4 lanes now hold u[h4]
      float b = __shfl_xor(a, 4, 64);     // partner row h4^1
      if ((tid & 7) == 0) su2[bg][h4 >> 1] = pkh2(a, b);
    }
    // P1b (S6): gates = Whh·d_prev (pure prev-state; y injected in S7)
    #pragma unroll 1
    for (int bg = 0; bg < BPB; ++bg) {
      const uint4* hr = (const uint4*)(const u32*)shp[bg];
      float a0 = biasD, a1 = 0.f, a2 = 0.f, a3 = 0.f;
      #pragma unroll
      for (int k = 0; k < 16; ++k) {
        uint4 hv = hr[k];
        a0 = dot2h(wpkD[4*k+0], hv.x, a0);
        a1 = dot2h(wpkD[4*k+1], hv.y, a1);
        a2 = dot2h(wpkD[4*k+2], hv.z, a2);
        a3 = dot2h(wpkD[4*k+3], hv.w, a3);
      }
      sg[bg][tid] = (a0 + a1) + (a2 + a3);
    }
    __syncthreads();
    // P2 (S2): score partials, packed fp16: thread (t=hh<100, q4), 32 h each
    if (hh < T_) {
      const uint2* wp  = (const uint2*)(sw2p + q4 * 16);
      const uint2* e0p = (const uint2*)(&sE1[0][hh * TS + q4 * 32]);
      const uint2* e1p = (const uint2*)(&sE1[1][hh * TS + q4 * 32]);
      const uint2* e2p = (const uint2*)(&sE1[2][hh * TS + q4 * 32]);
      const uint2* e3p = (const uint2*)(&sE1[3][hh * TS + q4 * 32]);
      const uint2* u0p = (const uint2*)(su2[0] + q4 * 16);
      const uint2* u1p = (const uint2*)(su2[1] + q4 * 16);
      const uint2* u2p = (const uint2*)(su2[2] + q4 * 16);
      const uint2* u3p = (const uint2*)(su2[3] + q4 * 16);
      float ac0 = 0.f, ac1 = 0.f, ac2 = 0.f, ac3 = 0.f;
      #pragma unroll
      for (int j = 0; j < 8; ++j) {
        uint2 w2v = wp[j];
        uint2 ev, uv;
        ev = e0p[j]; uv = u0p[j];
        ac0 = dot2h(w2v.x, tanhpk(ev.x, uv.x), ac0);
        ac0 = dot2h(w2v.y, tanhpk(ev.y, uv.y), ac0);
        ev = e1p[j]; uv = u1p[j];
        ac1 = dot2h(w2v.x, tanhpk(ev.x, uv.x), ac1);
        ac1 = dot2h(w2v.y, tanhpk(ev.y, uv.y), ac1);
        ev = e2p[j]; uv = u2p[j];
        ac2 = dot2h(w2v.x, tanhpk(ev.x, uv.x), ac2);
        ac2 = dot2h(w2v.y, tanhpk(ev.y, uv.y), ac2);
        ev = e3p[j]; uv = u3p[j];
        ac3 = dot2h(w2v.x, tanhpk(ev.x, uv.x), ac3);
        ac3 = dot2h(w2v.y, tanhpk(ev.y, uv.y), ac3);
      }
      spart[0][hh * 4 + q4] = ac0;
      spart[1][hh * 4 + q4] = ac1;
      spart[2][hh * 4 + q4] = ac2;
      spart[3][hh * 4 + q4] = ac3;
    }
    __syncthreads();
    // P3 (S3+S7): softmax + y for own quad (2-way redundant), then pointwise
    // LSTM with y-injection. sg untouched since P1; barrier only after.
    {
      float yv;
      {
        const int bg = q4;
        float4 p0 = ((const float4*)spart[bg])[lane];
        float e0 = __expf((p0.x + p0.y) + (p0.z + p0.w));
        float es = e0, ys = e0 * sye[bg][lane];
        if (lane < 36) {
          float4 p1 = ((const float4*)spart[bg])[64 + lane];
          float e1 = __expf((p1.x + p1.y) + (p1.z + p1.w));
          es += e1; ys += e1 * sye[bg][64 + lane];
        }
        es = wsum(es); ys = wsum(ys);
        yv = ys * rcpf_(es) + fcbv;
      }
      float gi = sigm(sg[q4][hh]        + wix * yv);
      float gf = sigm(sg[q4][hh + 128]  + wiy * yv);
      float gg = tanh_(sg[q4][hh + 256] + wiz * yv);
      float go = sigm(sg[q4][hh + 384]  + wiw * yv);
      float c  = gf * sc[q4][hh] + gi * gg;
      sc[q4][hh] = c;
      float d  = go * tanh_(c);
      sh[q4][hh] = d;
      shp[q4][hh] = f2h(d);
      scp[q4][hh] = f2h(c);
    }
    __syncthreads();
  }

  // ---------- final beta -> ctx -> head ----------
  if (wv < BPB) {                     // wave w computes beta for batch w
    int bg = wv;
    float4 p0 = ((const float4*)spart[bg])[lane];
    float e0 = __expf((p0.x + p0.y) + (p0.z + p0.w));
    float e1 = 0.f;
    if (lane < 36) {
      float4 p1 = ((const float4*)spart[bg])[64 + lane];
      e1 = __expf((p1.x + p1.y) + (p1.z + p1.w));
    }
    float iv = rcpf_(wsum(e0 + e1));
    sye[bg][lane] = e0 * iv;          // overwrite ye with beta
    if (lane < 36) sye[bg][64 + lane] = e1 * iv;
  }
  __syncthreads();
  {
    const u16* xeb = qws + (size_t)(b0 + q4) * QS + hh;
    float cx = 0.f;
    #pragma unroll 4
    for (int t = 0; t < T_; ++t)
      cx += sye[q4][t] * h2f(xeb[t * NT]);
    su[q4][hh] = cx;                  // ctx
  }
  __syncthreads();
  if (tid < BPB * C_) {
    int bg = tid >> 5, cls = tid & 31;
    const float* w = fcfW + (size_t)cls * 256;
    float acc = fcfb[cls];
    #pragma unroll 8
    for (int k = 0; k < 128; ++k)
      acc += w[k] * sh[bg][k] + w[128 + k] * su[bg][k];
    out[(size_t)(b0 + bg) * C_ + cls] = acc;
  }
}

// ================== fallback (R7 structure, no workspace) ==================
__global__ void __launch_bounds__(NT)
darnn_fb(const float* __restrict__ X,
         const float* __restrict__ eWih, const float* __restrict__ eWhh,
         const float* __restrict__ ebih, const float* __restrict__ ebhh,
         const float* __restrict__ eAw,
         const float* __restrict__ dW1,  const float* __restrict__ db1,
         const float* __restrict__ dW2,
         const float* __restrict__ dWih, const float* __restrict__ dWhh,
         const float* __restrict__ dbih, const float* __restrict__ dbhh,
         const float* __restrict__ fcW,  const float* __restrict__ fcb,
         const float* __restrict__ fcfW, const float* __restrict__ fcfb,
         float* __restrict__ out)
{
  __shared__ __align__(16) u16   sxh[12800];
  __shared__ __align__(16) u16   sXe[12800];
  __shared__ __align__(16) float sg[512];
  __shared__ __align__(16) float sh[128];
  __shared__ __align__(16) float sc[128];
  __shared__ __align__(16) u16   shp[128];
  __shared__ __align__(16) u16   scp[128];
  __shared__ __align__(16) float su[128];
  __shared__ __align__(16) float spart[512];
  __shared__ __align__(16) float sscore[128];
  __shared__ __align__(16) float sctx[128];
  __shared__ float sred[8];
  __shared__ float sredY[2];

  const int tid  = threadIdx.x;
  const int lane = tid & 63;
  const int wv   = tid >> 6;
  const int b    = blockIdx.x;
  const int hh   = tid & 127;
  const int q4   = tid >> 7;

  {
    const float4* Xb4 = (const float4*)(X + (size_t)b * 12800);
    u32* dst = (u32*)sxh;
    #pragma unroll
    for (int i = 0; i < 7; ++i) {
      int idx = tid + NT * i;
      if (idx < 3200) {
        float4 v = Xb4[idx];
        dst[2*idx]   = pkh2(v.x, v.y);
        dst[2*idx+1] = pkh2(v.z, v.w);
      }
    }
  }
  __syncthreads();
  float sval = 0.f;
  if (tid < 128) {
    #pragma unroll 4
    for (int t = 0; t < T_; ++t)
      sval += h2f(sxh[t * 128 + tid]) * eAw[256 + t];
  }
  float ee = (tid < 128) ? __expf(sval) : 0.f;
  float sm = wsum(ee);
  if (lane == 0 && wv < 2) sred[2 + wv] = sm;
  __syncthreads();
  if (tid < 128) {
    su[tid] = ee * rcpf_(sred[2] + sred[3]);
    sh[tid] = 0.f; sc[tid] = 0.f; shp[tid] = 0; scp[tid] = 0;
  }
  __syncthreads();
  {
    u32* sx32 = (u32*)sxh;
    #pragma unroll
    for (int i = 0; i < 13; ++i) {
      int p = tid + NT * i;
      if (p < 6400) {
        float lo, hi; unph(sx32[p], lo, hi);
        int m = (2 * p) & 127;
        sx32[p] = pkh2(lo * su[m], hi * su[m + 1]);
      }
    }
  }
  __syncthreads();

  u32 wpkH[64], wpkI[64];
  {
    const float4* wr = (const float4*)(eWhh + (size_t)tid * 128);
    #pragma unroll
    for (int i = 0; i < 32; ++i) {
      float4 v = wr[i];
      wpkH[2*i] = pkh2(v.x, v.y); wpkH[2*i+1] = pkh2(v.z, v.w);
    }
    const float4* wi = (const float4*)(eWih + (size_t)tid * 128);
    #pragma unroll
    for (int i = 0; i < 32; ++i) {
      float4 v = wi[i];
      wpkI[2*i] = pkh2(v.x, v.y); wpkI[2*i+1] = pkh2(v.z, v.w);
    }
  }
  float biasg = ebih[tid] + ebhh[tid];

  for (int t = 0; t < T_; ++t) {
    float a0 = biasg, a1 = 0.f, a2 = 0.f, a3 = 0.f;
    const uint4* hr = (const uint4*)(const u32*)shp;
    #pragma unroll
    for (int k = 0; k < 16; ++k) {
      uint4 hv = hr[k];
      a0 = dot2h(wpkH[4*k+0], hv.x, a0);
      a1 = dot2h(wpkH[4*k+1], hv.y, a1);
      a2 = dot2h(wpkH[4*k+2], hv.z, a2);
      a3 = dot2h(wpkH[4*k+3], hv.w, a3);
    }
    const uint4* xr = (const uint4*)((const u32*)sxh + t * 64);
    #pragma unroll
    for (int k = 0; k < 16; ++k) {
      uint4 xv = xr[k];
      a0 = dot2h(wpkI[4*k+0], xv.x, a0);
      a1 = dot2h(wpkI[4*k+1], xv.y, a1);
      a2 = dot2h(wpkI[4*k+2], xv.z, a2);
      a3 = dot2h(wpkI[4*k+3], xv.w, a3);
    }
    sg[tid] = (a0 + a1) + (a2 + a3);
    __syncthreads();
    if (tid < 128) {
      float gi = sigm(sg[tid]);
      float gf = sigm(sg[tid + 128]);
      float gg = tanh_(sg[tid + 256]);
      float go = sigm(sg[tid + 384]);
      float c  = gf * sc[tid] + gi * gg;
      sc[tid]  = c;
      float h  = go * tanh_(c);
      sh[tid]  = h;
      u16 hb = f2h(h);
      shp[tid] = hb; scp[tid] = f2h(c);
      sXe[t * 128 + tid] = hb;
    }
    __syncthreads();
  }

  {
    u32 wtp[64];
    const float4* w4 = (const float4*)(dW1 + (size_t)hh * 384 + 256);
    #pragma unroll
    for (int i = 0; i < 32; ++i) {
      float4 v = w4[i];
      wtp[2*i] = pkh2(v.x, v.y); wtp[2*i+1] = pkh2(v.z, v.w);
    }
    float b1v = db1[hh];
    u16 e1out[25];
    #pragma unroll 1
    for (int i = 0; i < 25; ++i) {
      int t = q4 * 25 + i;
      const uint4* xe4 = (const uint4*)(sXe + t * 128);
      float a0 = 0.f, a1 = 0.f;
      #pragma unroll
      for (int k = 0; k < 16; ++k) {
        uint4 xv = xe4[k];
        a0 = dot2h(wtp[4*k+0], xv.x, a0);
        a1 = dot2h(wtp[4*k+1], xv.y, a1);
        a0 = dot2h(wtp[4*k+2], xv.z, a0);
        a1 = dot2h(wtp[4*k+3], xv.w, a1);
      }
      e1out[i] = f2h(a0 + a1 + b1v);
    }
    __syncthreads();
    #pragma unroll 1
    for (int i = 0; i < 25; ++i)
      sxh[(q4 * 25 + i) * 128 + hh] = e1out[i];
  }

  u32 wpkD[64];
  {
    const float4* wr = (const float4*)(dWhh + (size_t)tid * 128);
    #pragma unroll
    for (int i = 0; i < 32; ++i) {
      float4 v = wr[i];
      wpkD[2*i] = pkh2(v.x, v.y); wpkD[2*i+1] = pkh2(v.z, v.w);
    }
  }
  u32 wtpU[32];
  {
    const float4* wu = (const float4*)(dW1 + (size_t)hh * 384 + q4 * 64);
    #pragma unroll
    for (int i = 0; i < 16; ++i) {
      float4 v = wu[i];
      wtpU[2*i] = pkh2(v.x, v.y); wtpU[2*i+1] = pkh2(v.z, v.w);
    }
  }
  float biasD = dbih[tid] + dbhh[tid];
  float wihj  = dWih[tid];
  float w2a   = dW2[lane];
  float w2b   = dW2[lane + 64];
  float fcbv  = fcb[0];
  float fcwv  = (tid < 128) ? fcW[tid] : 0.f;
  if (tid < 128) { sh[tid] = 0.f; sc[tid] = 0.f; shp[tid] = 0; scp[tid] = 0; }
  __syncthreads();

  for (int step = 0; step < T_; ++step) {
    {
      const u32* base = (q4 < 2) ? (const u32*)shp : (const u32*)scp;
      const uint4* vp = (const uint4*)(base + (q4 & 1) * 32);
      float a0 = 0.f, a1 = 0.f;
      #pragma unroll
      for (int k = 0; k < 8; ++k) {
        uint4 v = vp[k];
        a0 = dot2h(wtpU[4*k+0], v.x, a0);
        a1 = dot2h(wtpU[4*k+1], v.y, a1);
        a0 = dot2h(wtpU[4*k+2], v.z, a0);
        a1 = dot2h(wtpU[4*k+3], v.w, a1);
      }
      spart[q4 * 128 + hh] = a0 + a1;
    }
    __syncthreads();
    {
      float ul = spart[lane] + spart[128 + lane]
               + spart[256 + lane] + spart[384 + lane];
      float uh = spart[64 + lane] + spart[192 + lane]
               + spart[320 + lane] + spart[448 + lane];
      #pragma unroll 1
      for (int i = 0; i < 13; ++i) {
        int t = wv + 8 * i;
        if (t < T_) {
          float v = w2a * ptanh(h2f(sxh[t * 128 + lane]) + ul)
                  + w2b * ptanh(h2f(sxh[t * 128 + 64 + lane]) + uh);
          v = wsum(v);
          if (lane == 0) sscore[t] = v;
        }
      }
    }
    __syncthreads();
    if (wv == 0) {
      float s0 = sscore[lane];
      float E0 = __expf(s0);
      float E1v = (lane < 36) ? __expf(sscore[lane + 64]) : 0.f;
      float s  = wsum(E0 + E1v);
      float iv = rcpf_(s);
      sscore[lane] = E0 * iv;
      if (lane < 36) sscore[lane + 64] = E1v * iv;
    }
    __syncthreads();
    {
      float pc = 0.f;
      #pragma unroll
      for (int i = 0; i < 25; ++i) {
        int t = q4 * 25 + i;
        pc += sscore[t] * h2f(sXe[t * 128 + hh]);
      }
      spart[q4 * 128 + hh] = pc;
    }
    __syncthreads();
    {
      float v = 0.f;
      if (tid < 128) {
        float cx = spart[tid] + spart[tid + 128]
                 + spart[tid + 256] + spart[tid + 384];
        sctx[tid] = cx;
        v = fcwv * cx;
      }
      v = wsum(v);
      if (lane == 0 && wv < 2) sredY[wv] = v;
    }
    __syncthreads();
    {
      float yt = sredY[0] + sredY[1] + fcbv;
      float a0 = biasD + wihj * yt, a1 = 0.f, a2 = 0.f, a3 = 0.f;
      const uint4* hr = (const uint4*)(const u32*)shp;
      #pragma unroll
      for (int k = 0; k < 16; ++k) {
        uint4 hv = hr[k];
        a0 = dot2h(wpkD[4*k+0], hv.x, a0);
        a1 = dot2h(wpkD[4*k+1], hv.y, a1);
        a2 = dot2h(wpkD[4*k+2], hv.z, a2);
        a3 = dot2h(wpkD[4*k+3], hv.w, a3);
      }
      sg[tid] = (a0 + a1) + (a2 + a3);
    }
    __syncthreads();
    if (tid < 128) {
      float gi = sigm(sg[tid]);
      float gf = sigm(sg[tid + 128]);
      float gg = tanh_(sg[tid + 256]);
      float go = sigm(sg[tid + 384]);
      float c  = gf * sc[tid] + gi * gg;
      sc[tid]  = c;
      float d  = go * tanh_(c);
      sh[tid]  = d;
      shp[tid] = f2h(d);
      scp[tid] = f2h(c);
    }
    __syncthreads();
  }

  if (tid < C_) {
    float acc = fcfb[tid];
    const float* w = fcfW + (size_t)tid * 256;
    #pragma unroll 8
    for (int k = 0; k < 128; ++k)
      acc += w[k] * sh[k] + w[128 + k] * sctx[k];
    out[(size_t)b * C_ + tid] = acc;
  }
}

extern "C" void kernel_launch(void* const* d_in, const int* in_sizes, int n_in,
                              void* d_out, int out_size, void* d_ws, size_t ws_size,
                              hipStream_t stream) {
  (void)n_in; (void)out_size;
  const float* X    = (const float*)d_in[0];
  const float* eWih = (const float*)d_in[1];
  const float* eWhh = (const float*)d_in[2];
  const float* ebih = (const float*)d_in[3];
  const float* ebhh = (const float*)d_in[4];
  const float* eAw  = (const float*)d_in[5];
  const float* eAb  = (const float*)d_in[6];
  const float* dW1  = (const float*)d_in[7];
  const float* db1  = (const float*)d_in[8];
  const float* dW2  = (const float*)d_in[9];
  const float* db2  = (const float*)d_in[10];
  const float* dWih = (const float*)d_in[11];
  const float* dWhh = (const float*)d_in[12];
  const float* dbih = (const float*)d_in[13];
  const float* dbhh = (const float*)d_in[14];
  const float* fcW  = (const float*)d_in[15];
  const float* fcb  = (const float*)d_in[16];
  const float* fcfW = (const float*)d_in[17];
  const float* fcfb = (const float*)d_in[18];
  float* out = (float*)d_out;

  const int B = in_sizes[0] / (T_ * 128);
  const size_t needQ = (size_t)B * QS * sizeof(u16);
  if (ws_size >= needQ && (B % BPB) == 0) {
    darnn4<<<dim3(B / BPB), dim3(NT), 0, stream>>>(
        X, eWih, eWhh, ebih, ebhh, eAw, eAb,
        dW1, db1, dW2, db2, dWih, dWhh, dbih, dbhh,
        fcW, fcb, fcfW, fcfb, (u16*)d_ws, out);
  } else {
    darnn_fb<<<dim3(B), dim3(NT), 0, stream>>>(
        X, eWih, eWhh, ebih, ebhh, eAw,
        dW1, db1, dW2, dWih, dWhh, dbih, dbhh,
        fcW, fcb, fcfW, fcfb, out);
  }
}

// Round 9
// 734.195 us; speedup vs baseline: 1.5385x; 1.5385x over previous
//
#include <hip/hip_runtime.h>

// DA-RNN fused — R17: recurrent GEMVs on the MATRIX pipe.
//  * R16 flat -> kernel is VALU-issue-bound (~97K instr/thread), MfmaUtil=0.
//  * R17: batched-GEMV gates as v_mfma_f32_16x16x32_f16, N=16 (4 batches +
//    12 ignored cols): enc gates & dec S6 = 16 MFMA/wave/step (was 256 dot2h);
//    dec S0 = 8 MFMA (was 128 dot2h). A-frags preloaded (64/32 VGPR, 1:1
//    replacing wpkH/wpkD/wtpU). Layout-robust: same k-slot convention on A and
//    B => correct under any bijective HW k-map; C/D layout is the HW-verified
//    col=lane&15, row=(lane>>4)*4+reg.
//  * Biases + Q-term + y-term move to pointwise (4 preloaded scalars each);
//    Q prefetched into regs at phase-A top (new barrier after Q GEMM — Q now
//    cross-thread). shp/scp padded to 160 u16 (bg-stride=16 banks -> 2-way
//    free on B-frag gathers); sg->520, su2->68 pads (2-way writes).
//  * Q GEMM / E1 / S2 / S3 / alpha / ye / head unchanged from R16.

typedef unsigned int   u32;
typedef unsigned short u16;

#define T_  100
#define C_  32
#define NT  512
#define BPB 4
#define TS  132
#define QS  (T_ * NT)
#define SP  160   // shp/scp padded row (u16)

typedef __attribute__((ext_vector_type(2))) __fp16 h16x2;
typedef __attribute__((ext_vector_type(8))) __fp16 h16x8;
typedef __attribute__((ext_vector_type(4))) float  f32x4;

#if __has_builtin(__builtin_amdgcn_fdot2)
#define HAVE_FDOT2 1
#else
#define HAVE_FDOT2 0
#endif

__device__ __forceinline__ u32 pkh2(float a, float b) {
#if __has_builtin(__builtin_amdgcn_cvt_pkrtz)
  h16x2 p = __builtin_amdgcn_cvt_pkrtz(a, b);
  return __builtin_bit_cast(u32, p);
#else
  union { __fp16 h[2]; u32 u; } v;
  v.h[0] = (__fp16)a; v.h[1] = (__fp16)b;
  return v.u;
#endif
}
__device__ __forceinline__ void unph(u32 p, float& lo, float& hi) {
  union { u32 u; __fp16 h[2]; } v; v.u = p;
  lo = (float)v.h[0]; hi = (float)v.h[1];
}
__device__ __forceinline__ u16 f2h(float f) {
  union { __fp16 h; u16 u; } v; v.h = (__fp16)f; return v.u;
}
__device__ __forceinline__ float h2f(u16 u) {
  union { u16 u; __fp16 h; } v; v.u = u; return (float)v.h;
}
__device__ __forceinline__ float dot2h(u32 w, u32 x, float acc) {
#if HAVE_FDOT2
  return __builtin_amdgcn_fdot2(__builtin_bit_cast(h16x2, w),
                                __builtin_bit_cast(h16x2, x),
                                acc, false);
#else
  float a, b, c, d;
  unph(w, a, b); unph(x, c, d);
  return fmaf(a, c, fmaf(b, d, acc));
#endif
}
// pack 8 consecutive floats at p into 8 fp16 (A-fragment)
__device__ __forceinline__ h16x8 pack8(const float* p) {
  float4 v0 = *(const float4*)p;
  float4 v1 = *(const float4*)(p + 4);
  uint4 u;
  u.x = pkh2(v0.x, v0.y); u.y = pkh2(v0.z, v0.w);
  u.z = pkh2(v1.x, v1.y); u.w = pkh2(v1.z, v1.w);
  return __builtin_bit_cast(h16x8, u);
}
// load 8 consecutive fp16 from LDS (B-fragment)
__device__ __forceinline__ h16x8 ldb(const u16* p, int off) {
  return __builtin_bit_cast(h16x8, *(const uint4*)(p + off));
}

#if __has_builtin(__builtin_amdgcn_rcpf)
__device__ __forceinline__ float rcpf_(float x){ return __builtin_amdgcn_rcpf(x); }
#else
__device__ __forceinline__ float rcpf_(float x){ return 1.0f / x; }
#endif
__device__ __forceinline__ float sigm(float x){ return rcpf_(1.0f + __expf(-x)); }
__device__ __forceinline__ float tanh_(float x){
  return 1.0f - 2.0f * rcpf_(1.0f + __expf(2.0f * x));
}
// packed-fp16 tanh approx of (e+u), both packed half2 as u32
__device__ __forceinline__ u32 tanhpk(u32 eu, u32 uu) {
  h16x2 x = __builtin_bit_cast(h16x2, eu) + __builtin_bit_cast(h16x2, uu);
  const h16x2 one  = {(__fp16)1.0f,  (__fp16)1.0f};
#if __has_builtin(__builtin_elementwise_max) && __has_builtin(__builtin_elementwise_min)
  const h16x2 mone = {(__fp16)-1.0f, (__fp16)-1.0f};
  x = __builtin_elementwise_min(one, __builtin_elementwise_max(x, mone));
#else
  {
    float lo, hi; unph(__builtin_bit_cast(u32, x), lo, hi);
    x = (h16x2){(__fp16)fminf(1.f, fmaxf(-1.f, lo)),
                (__fp16)fminf(1.f, fmaxf(-1.f, hi))};
  }
#endif
  h16x2 x2 = x * x;
  const h16x2 c1 = {(__fp16)0.1333333f,  (__fp16)0.1333333f};
  const h16x2 c0 = {(__fp16)-0.3333333f, (__fp16)-0.3333333f};
  h16x2 r = x * (x2 * (x2 * c1 + c0) + one);
  return __builtin_bit_cast(u32, r);
}
__device__ __forceinline__ float ptanh(float x){
  x = fminf(1.0f, fmaxf(-1.0f, x));
  float x2 = x * x;
  float p  = fmaf(x2, 0.1333333f, -0.3333333f);
  return x * fmaf(x2, p, 1.0f);
}
__device__ __forceinline__ float wsum(float v){
  #pragma unroll
  for (int o = 32; o; o >>= 1) v += __shfl_xor(v, o, 64);
  return v;
}

// ============================ fast kernel (4 batches/block) =================
__global__ void __launch_bounds__(NT)
darnn4(const float* __restrict__ X,
       const float* __restrict__ eWih, const float* __restrict__ eWhh,
       const float* __restrict__ ebih, const float* __restrict__ ebhh,
       const float* __restrict__ eAw,  const float* __restrict__ eAb,
       const float* __restrict__ dW1,  const float* __restrict__ db1,
       const float* __restrict__ dW2,  const float* __restrict__ db2,
       const float* __restrict__ dWih, const float* __restrict__ dWhh,
       const float* __restrict__ dbih, const float* __restrict__ dbhh,
       const float* __restrict__ fcW,  const float* __restrict__ fcb,
       const float* __restrict__ fcfW, const float* __restrict__ fcfb,
       u16* __restrict__ qws,
       float* __restrict__ out)
{
  // LDS ~131.1 KB
  __shared__ __align__(16) u16   sE1[BPB][T_ * TS];  // x_tilde -> E1   105600
  __shared__ __align__(16) float sg[BPB][520];       // gates (padded)   8320
  __shared__ __align__(16) float sh[BPB][128];       // h/d fp32         2048
  __shared__ __align__(16) float sc[BPB][128];       // c fp32           2048
  __shared__ __align__(16) u16   shp[BPB][SP];       // h/d fp16 (pad)   1280
  __shared__ __align__(16) u16   scp[BPB][SP];       // c fp16 (pad)     1280
  __shared__ __align__(16) float su[BPB][128];       // ctx              2048
  __shared__ __align__(16) float spart[BPB][512];    // partials         8192
  __shared__ __align__(16) float sye[BPB][128];      // ye -> beta       2048
  __shared__ __align__(16) u32   su2[BPB][68];       // packed u (pad)   1088
  __shared__ __align__(16) u32   sw2p[64];           // packed w2         256
  __shared__ float sred[16];

  const int tid  = threadIdx.x;
  const int lane = tid & 63;
  const int wv   = tid >> 6;     // 0..7
  const int hh   = tid & 127;
  const int q4   = tid >> 7;     // 0..3
  const int nn   = lane & 15;    // MFMA col (batch when <4)
  const int kg   = lane >> 4;    // MFMA k-group
  const bool wr  = (nn < BPB);   // this lane writes MFMA results
  const int b0   = blockIdx.x * BPB;

  (void)eAb; (void)db2;          // cancel under softmax shift-invariance

  if (tid < 64) sw2p[tid] = pkh2(dW2[2 * tid], dW2[2 * tid + 1]);

  // ---------- alpha (no max-sub; h/c terms cancel) + x_tilde ----------
  {
    const float* xp = X + (size_t)(b0 + q4) * 12800 + hh;
    float sval = 0.f;
    #pragma unroll 4
    for (int t = 0; t < T_; ++t) sval += xp[t * 128] * eAw[256 + t];
    float e = __expf(sval);
    float s = wsum(e);
    if (lane == 0) sred[wv] = s;
    __syncthreads();
    float al = e * rcpf_(sred[q4 * 2] + sred[q4 * 2 + 1]);
    #pragma unroll 4
    for (int t = 0; t < T_; ++t)
      sE1[q4][t * TS + hh] = f2h(al * xp[t * 128]);
    sh[q4][hh] = 0.f; sc[q4][hh] = 0.f; shp[q4][hh] = 0; scp[q4][hh] = 0;
  }
  __syncthreads();

  // ---------- Q GEMM: Q[b][t][r] = eWih[r,:]·x_tilde ----------
  {
    u32 wq[64];
    const float4* wi = (const float4*)(eWih + (size_t)tid * 128);
    #pragma unroll
    for (int i = 0; i < 32; ++i) {
      float4 v = wi[i];
      wq[2*i]   = pkh2(v.x, v.y);
      wq[2*i+1] = pkh2(v.z, v.w);
    }
    #pragma unroll 1
    for (int bg = 0; bg < BPB; ++bg) {
      u16* qb = qws + (size_t)(b0 + bg) * QS;
      #pragma unroll 1
      for (int t = 0; t < T_; ++t) {
        const uint2* xr = (const uint2*)(&sE1[bg][t * TS]);
        float a0 = 0.f, a1 = 0.f;
        #pragma unroll
        for (int k = 0; k < 16; ++k) {
          uint2 xv = xr[k];
          a0 = dot2h(wq[2*k],   xv.x, a0);
          a1 = dot2h(wq[2*k+1], xv.y, a1);
        }
        qb[t * NT + tid] = f2h(a0 + a1);
      }
    }
  }
  __syncthreads();   // Q now consumed cross-thread by encoder pointwise

  // ---------- encoder (MFMA gates; 2 barriers/step) ----------
  {
    // A-frags: eWhh rows [wv*64, +64), 4 row-tiles x 4 K-steps
    h16x8 aH[16];
    #pragma unroll
    for (int rt = 0; rt < 4; ++rt)
      #pragma unroll
      for (int ks = 0; ks < 4; ++ks)
        aH[rt*4+ks] = pack8(eWhh + (size_t)(wv*64 + rt*16 + nn) * 128
                            + ks*32 + kg*8);
    float bgx = ebih[hh]       + ebhh[hh];
    float bgy = ebih[hh + 128] + ebhh[hh + 128];
    float bgz = ebih[hh + 256] + ebhh[hh + 256];
    float bgw = ebih[hh + 384] + ebhh[hh + 384];
    const u16* qrow = qws + (size_t)(b0 + q4) * QS + hh;

    for (int t = 0; t < T_; ++t) {
      // prefetch this thread's 4 Q values (consumed in pointwise)
      u16 qv0 = qrow[t * NT];
      u16 qv1 = qrow[t * NT + 128];
      u16 qv2 = qrow[t * NT + 256];
      u16 qv3 = qrow[t * NT + 384];
      // gates = eWhh · h_prev  (cols 0..3 = batches, 4..15 ignored)
      f32x4 g0 = {0,0,0,0}, g1 = {0,0,0,0}, g2 = {0,0,0,0}, g3 = {0,0,0,0};
      #pragma unroll
      for (int ks = 0; ks < 4; ++ks) {
        h16x8 b = ldb(&shp[nn & 3][0], ks*32 + kg*8);
        g0 = __builtin_amdgcn_mfma_f32_16x16x32_f16(aH[0*4+ks], b, g0, 0,0,0);
        g1 = __builtin_amdgcn_mfma_f32_16x16x32_f16(aH[1*4+ks], b, g1, 0,0,0);
        g2 = __builtin_amdgcn_mfma_f32_16x16x32_f16(aH[2*4+ks], b, g2, 0,0,0);
        g3 = __builtin_amdgcn_mfma_f32_16x16x32_f16(aH[3*4+ks], b, g3, 0,0,0);
      }
      if (wr) {
        *(f32x4*)(&sg[nn][wv*64 +  0 + kg*4]) = g0;
        *(f32x4*)(&sg[nn][wv*64 + 16 + kg*4]) = g1;
        *(f32x4*)(&sg[nn][wv*64 + 32 + kg*4]) = g2;
        *(f32x4*)(&sg[nn][wv*64 + 48 + kg*4]) = g3;
      }
      __syncthreads();
      {
        float gi = sigm (sg[q4][hh]       + bgx + h2f(qv0));
        float gf = sigm (sg[q4][hh + 128] + bgy + h2f(qv1));
        float gg = tanh_(sg[q4][hh + 256] + bgz + h2f(qv2));
        float go = sigm (sg[q4][hh + 384] + bgw + h2f(qv3));
        float c  = gf * sc[q4][hh] + gi * gg;
        sc[q4][hh] = c;
        float h  = go * tanh_(c);
        sh[q4][hh] = h;
        u16 hb = f2h(h);
        shp[q4][hh] = hb;
        scp[q4][hh] = f2h(c);
        // Xe row t shares Q's slab (Q[t] consumed pre-barrier; reg-held)
        qws[(size_t)(b0 + q4) * QS + t * NT + hh] = hb;
      }
      __syncthreads();
    }
  }

  // ---------- ye[t] = fcW · Xe[t]  ----------
  if (hh < T_) {
    #pragma unroll 1
    for (int bg = 0; bg < BPB; ++bg) {
      const uint2* xe = (const uint2*)(qws + (size_t)(b0 + bg) * QS
                                       + hh * NT + q4 * 32);
      const float* fw = fcW + q4 * 32;
      float a = 0.f;
      #pragma unroll
      for (int k = 0; k < 8; ++k) {
        uint2 xv = xe[k];
        float l0, l1, l2, l3;
        unph(xv.x, l0, l1); unph(xv.y, l2, l3);
        a += fw[4*k]*l0 + fw[4*k+1]*l1 + fw[4*k+2]*l2 + fw[4*k+3]*l3;
      }
      spart[bg][hh * 4 + q4] = a;
    }
  }
  __syncthreads();
  if (hh < T_) {
    float4 p = ((const float4*)spart[q4])[hh];
    sye[q4][hh] = (p.x + p.y) + (p.z + p.w);
  }
  __syncthreads();

  // ---------- E1[t][h] = dW1[h][256:384]·Xe[t] + db1[h] -> LDS ----------
  {
    u32 wtp[64];
    const float4* w4p = (const float4*)(dW1 + (size_t)hh * 384 + 256);
    #pragma unroll
    for (int i = 0; i < 32; ++i) {
      float4 v = w4p[i];
      wtp[2*i]   = pkh2(v.x, v.y);
      wtp[2*i+1] = pkh2(v.z, v.w);
    }
    float b1v = db1[hh];
    #pragma unroll 1
    for (int bg = 0; bg < BPB; ++bg) {
      #pragma unroll 1
      for (int i = 0; i < 25; ++i) {
        int t = q4 * 25 + i;
        const uint2* xe = (const uint2*)(qws + (size_t)(b0 + bg) * QS + t * NT);
        float a0 = 0.f, a1 = 0.f;
        #pragma unroll
        for (int k = 0; k < 16; ++k) {
          uint2 xv = xe[k];
          a0 = dot2h(wtp[2*k],   xv.x, a0);
          a1 = dot2h(wtp[2*k+1], xv.y, a1);
        }
        sE1[bg][t * TS + hh] = f2h(a0 + a1 + b1v);
      }
    }
  }

  // ---------- decoder weights (MFMA A-fragments) ----------
  h16x8 aD[16];   // dWhh rows [wv*64, +64)
  #pragma unroll
  for (int rt = 0; rt < 4; ++rt)
    #pragma unroll
    for (int ks = 0; ks < 4; ++ks)
      aD[rt*4+ks] = pack8(dWhh + (size_t)(wv*64 + rt*16 + nn) * 128
                          + ks*32 + kg*8);
  h16x8 aU[8];    // dW1 z-part rows [wv*16, +16), cols 0..255
  #pragma unroll
  for (int ks = 0; ks < 8; ++ks)
    aU[ks] = pack8(dW1 + (size_t)(wv*16 + nn) * 384 + ks*32 + kg*8);
  float bdx = dbih[hh]       + dbhh[hh];
  float bdy = dbih[hh + 128] + dbhh[hh + 128];
  float bdz = dbih[hh + 256] + dbhh[hh + 256];
  float bdw = dbih[hh + 384] + dbhh[hh + 384];
  float wix = dWih[hh];
  float wiy = dWih[hh + 128];
  float wiz = dWih[hh + 256];
  float wiw = dWih[hh + 384];
  float fcbv = fcb[0];
  sh[q4][hh] = 0.f; sc[q4][hh] = 0.f; shp[q4][hh] = 0; scp[q4][hh] = 0;
  __syncthreads();

  // ---------- decoder (3 barriers/step) ----------
  for (int step = 0; step < T_; ++step) {
    // P1a (S0, MFMA): u = dW1z · [d;c]; wave wv owns u-rows [wv*16,+16)
    {
      f32x4 au = {0,0,0,0};
      #pragma unroll
      for (int ks = 0; ks < 8; ++ks) {
        const u16* bp = (ks < 4) ? &shp[nn & 3][0] : &scp[nn & 3][0];
        h16x8 b = ldb(bp, (ks & 3)*32 + kg*8);
        au = __builtin_amdgcn_mfma_f32_16x16x32_f16(aU[ks], b, au, 0,0,0);
      }
      if (wr) {
        uint2 up;
        up.x = pkh2(au[0], au[1]);
        up.y = pkh2(au[2], au[3]);
        *(uint2*)(&su2[nn][wv*8 + kg*2]) = up;
      }
    }
    // P1b (S6, MFMA): gates = dWhh · d_prev
    {
      f32x4 g0 = {0,0,0,0}, g1 = {0,0,0,0}, g2 = {0,0,0,0}, g3 = {0,0,0,0};
      #pragma unroll
      for (int ks = 0; ks < 4; ++ks) {
        h16x8 b = ldb(&shp[nn & 3][0], ks*32 + kg*8);
        g0 = __builtin_amdgcn_mfma_f32_16x16x32_f16(aD[0*4+ks], b, g0, 0,0,0);
        g1 = __builtin_amdgcn_mfma_f32_16x16x32_f16(aD[1*4+ks], b, g1, 0,0,0);
        g2 = __builtin_amdgcn_mfma_f32_16x16x32_f16(aD[2*4+ks], b, g2, 0,0,0);
        g3 = __builtin_amdgcn_mfma_f32_16x16x32_f16(aD[3*4+ks], b, g3, 0,0,0);
      }
      if (wr) {
        *(f32x4*)(&sg[nn][wv*64 +  0 + kg*4]) = g0;
        *(f32x4*)(&sg[nn][wv*64 + 16 + kg*4]) = g1;
        *(f32x4*)(&sg[nn][wv*64 + 32 + kg*4]) = g2;
        *(f32x4*)(&sg[nn][wv*64 + 48 + kg*4]) = g3;
      }
    }
    __syncthreads();
    // P2 (S2): score partials, packed fp16: thread (t=hh<100, q4), 32 h each
    if (hh < T_) {
      const uint2* wp  = (const uint2*)(sw2p + q4 * 16);
      const uint2* e0p = (const uint2*)(&sE1[0][hh * TS + q4 * 32]);
      const uint2* e1p = (const uint2*)(&sE1[1][hh * TS + q4 * 32]);
      const uint2* e2p = (const uint2*)(&sE1[2][hh * TS + q4 * 32]);
      const uint2* e3p = (const uint2*)(&sE1[3][hh * TS + q4 * 32]);
      const uint2* u0p = (const uint2*)(su2[0] + q4 * 16);
      const uint2* u1p = (const uint2*)(su2[1] + q4 * 16);
      const uint2* u2p = (const uint2*)(su2[2] + q4 * 16);
      const uint2* u3p = (const uint2*)(su2[3] + q4 * 16);
      float ac0 = 0.f, ac1 = 0.f, ac2 = 0.f, ac3 = 0.f;
      #pragma unroll
      for (int j = 0; j < 8; ++j) {
        uint2 w2v = wp[j];
        uint2 ev, uv;
        ev = e0p[j]; uv = u0p[j];
        ac0 = dot2h(w2v.x, tanhpk(ev.x, uv.x), ac0);
        ac0 = dot2h(w2v.y, tanhpk(ev.y, uv.y), ac0);
        ev = e1p[j]; uv = u1p[j];
        ac1 = dot2h(w2v.x, tanhpk(ev.x, uv.x), ac1);
        ac1 = dot2h(w2v.y, tanhpk(ev.y, uv.y), ac1);
        ev = e2p[j]; uv = u2p[j];
        ac2 = dot2h(w2v.x, tanhpk(ev.x, uv.x), ac2);
        ac2 = dot2h(w2v.y, tanhpk(ev.y, uv.y), ac2);
        ev = e3p[j]; uv = u3p[j];
        ac3 = dot2h(w2v.x, tanhpk(ev.x, uv.x), ac3);
        ac3 = dot2h(w2v.y, tanhpk(ev.y, uv.y), ac3);
      }
      spart[0][hh * 4 + q4] = ac0;
      spart[1][hh * 4 + q4] = ac1;
      spart[2][hh * 4 + q4] = ac2;
      spart[3][hh * 4 + q4] = ac3;
    }
    __syncthreads();
    // P3 (S3+S7): softmax + y for own quad; pointwise LSTM with bias+y inject
    {
      float yv;
      {
        const int bg = q4;
        float4 p0 = ((const float4*)spart[bg])[lane];
        float e0 = __expf((p0.x + p0.y) + (p0.z + p0.w));
        float es = e0, ys = e0 * sye[bg][lane];
        if (lane < 36) {
          float4 p1 = ((const float4*)spart[bg])[64 + lane];
          float e1 = __expf((p1.x + p1.y) + (p1.z + p1.w));
          es += e1; ys += e1 * sye[bg][64 + lane];
        }
        es = wsum(es); ys = wsum(ys);
        yv = ys * rcpf_(es) + fcbv;
      }
      float gi = sigm (sg[q4][hh]       + bdx + wix * yv);
      float gf = sigm (sg[q4][hh + 128] + bdy + wiy * yv);
      float gg = tanh_(sg[q4][hh + 256] + bdz + wiz * yv);
      float go = sigm (sg[q4][hh + 384] + bdw + wiw * yv);
      float c  = gf * sc[q4][hh] + gi * gg;
      sc[q4][hh] = c;
      float d  = go * tanh_(c);
      sh[q4][hh] = d;
      shp[q4][hh] = f2h(d);
      scp[q4][hh] = f2h(c);
    }
    __syncthreads();
  }

  // ---------- final beta -> ctx -> head ----------
  if (wv < BPB) {                     // wave w computes beta for batch w
    int bg = wv;
    float4 p0 = ((const float4*)spart[bg])[lane];
    float e0 = __expf((p0.x + p0.y) + (p0.z + p0.w));
    float e1 = 0.f;
    if (lane < 36) {
      float4 p1 = ((const float4*)spart[bg])[64 + lane];
      e1 = __expf((p1.x + p1.y) + (p1.z + p1.w));
    }
    float iv = rcpf_(wsum(e0 + e1));
    sye[bg][lane] = e0 * iv;          // overwrite ye with beta
    if (lane < 36) sye[bg][64 + lane] = e1 * iv;
  }
  __syncthreads();
  {
    const u16* xeb = qws + (size_t)(b0 + q4) * QS + hh;
    float cx = 0.f;
    #pragma unroll 4
    for (int t = 0; t < T_; ++t)
      cx += sye[q4][t] * h2f(xeb[t * NT]);
    su[q4][hh] = cx;                  // ctx
  }
  __syncthreads();
  if (tid < BPB * C_) {
    int bg = tid >> 5, cls = tid & 31;
    const float* w = fcfW + (size_t)cls * 256;
    float acc = fcfb[cls];
    #pragma unroll 8
    for (int k = 0; k < 128; ++k)
      acc += w[k] * sh[bg][k] + w[128 + k] * su[bg][k];
    out[(size_t)(b0 + bg) * C_ + cls] = acc;
  }
}

// ================== fallback (R7 structure, no workspace) ==================
__global__ void __launch_bounds__(NT)
darnn_fb(const float* __restrict__ X,
         const float* __restrict__ eWih, const float* __restrict__ eWhh,
         const float* __restrict__ ebih, const float* __restrict__ ebhh,
         const float* __restrict__ eAw,
         const float* __restrict__ dW1,  const float* __restrict__ db1,
         const float* __restrict__ dW2,
         const float* __restrict__ dWih, const float* __restrict__ dWhh,
         const float* __restrict__ dbih, const float* __restrict__ dbhh,
         const float* __restrict__ fcW,  const float* __restrict__ fcb,
         const float* __restrict__ fcfW, const float* __restrict__ fcfb,
         float* __restrict__ out)
{
  __shared__ __align__(16) u16   sxh[12800];
  __shared__ __align__(16) u16   sXe[12800];
  __shared__ __align__(16) float sg[512];
  __shared__ __align__(16) float sh[128];
  __shared__ __align__(16) float sc[128];
  __shared__ __align__(16) u16   shp[128];
  __shared__ __align__(16) u16   scp[128];
  __shared__ __align__(16) float su[128];
  __shared__ __align__(16) float spart[512];
  __shared__ __align__(16) float sscore[128];
  __shared__ __align__(16) float sctx[128];
  __shared__ float sred[8];
  __shared__ float sredY[2];

  const int tid  = threadIdx.x;
  const int lane = tid & 63;
  const int wv   = tid >> 6;
  const int b    = blockIdx.x;
  const int hh   = tid & 127;
  const int q4   = tid >> 7;

  {
    const float4* Xb4 = (const float4*)(X + (size_t)b * 12800);
    u32* dst = (u32*)sxh;
    #pragma unroll
    for (int i = 0; i < 7; ++i) {
      int idx = tid + NT * i;
      if (idx < 3200) {
        float4 v = Xb4[idx];
        dst[2*idx]   = pkh2(v.x, v.y);
        dst[2*idx+1] = pkh2(v.z, v.w);
      }
    }
  }
  __syncthreads();
  float sval = 0.f;
  if (tid < 128) {
    #pragma unroll 4
    for (int t = 0; t < T_; ++t)
      sval += h2f(sxh[t * 128 + tid]) * eAw[256 + t];
  }
  float ee = (tid < 128) ? __expf(sval) : 0.f;
  float sm = wsum(ee);
  if (lane == 0 && wv < 2) sred[2 + wv] = sm;
  __syncthreads();
  if (tid < 128) {
    su[tid] = ee * rcpf_(sred[2] + sred[3]);
    sh[tid] = 0.f; sc[tid] = 0.f; shp[tid] = 0; scp[tid] = 0;
  }
  __syncthreads();
  {
    u32* sx32 = (u32*)sxh;
    #pragma unroll
    for (int i = 0; i < 13; ++i) {
      int p = tid + NT * i;
      if (p < 6400) {
        float lo, hi; unph(sx32[p], lo, hi);
        int m = (2 * p) & 127;
        sx32[p] = pkh2(lo * su[m], hi * su[m + 1]);
      }
    }
  }
  __syncthreads();

  u32 wpkH[64], wpkI[64];
  {
    const float4* wr = (const float4*)(eWhh + (size_t)tid * 128);
    #pragma unroll
    for (int i = 0; i < 32; ++i) {
      float4 v = wr[i];
      wpkH[2*i] = pkh2(v.x, v.y); wpkH[2*i+1] = pkh2(v.z, v.w);
    }
    const float4* wi = (const float4*)(eWih + (size_t)tid * 128);
    #pragma unroll
    for (int i = 0; i < 32; ++i) {
      float4 v = wi[i];
      wpkI[2*i] = pkh2(v.x, v.y); wpkI[2*i+1] = pkh2(v.z, v.w);
    }
  }
  float biasg = ebih[tid] + ebhh[tid];

  for (int t = 0; t < T_; ++t) {
    float a0 = biasg, a1 = 0.f, a2 = 0.f, a3 = 0.f;
    const uint4* hr = (const uint4*)(const u32*)shp;
    #pragma unroll
    for (int k = 0; k < 16; ++k) {
      uint4 hv = hr[k];
      a0 = dot2h(wpkH[4*k+0], hv.x, a0);
      a1 = dot2h(wpkH[4*k+1], hv.y, a1);
      a2 = dot2h(wpkH[4*k+2], hv.z, a2);
      a3 = dot2h(wpkH[4*k+3], hv.w, a3);
    }
    const uint4* xr = (const uint4*)((const u32*)sxh + t * 64);
    #pragma unroll
    for (int k = 0; k < 16; ++k) {
      uint4 xv = xr[k];
      a0 = dot2h(wpkI[4*k+0], xv.x, a0);
      a1 = dot2h(wpkI[4*k+1], xv.y, a1);
      a2 = dot2h(wpkI[4*k+2], xv.z, a2);
      a3 = dot2h(wpkI[4*k+3], xv.w, a3);
    }
    sg[tid] = (a0 + a1) + (a2 + a3);
    __syncthreads();
    if (tid < 128) {
      float gi = sigm(sg[tid]);
      float gf = sigm(sg[tid + 128]);
      float gg = tanh_(sg[tid + 256]);
      float go = sigm(sg[tid + 384]);
      float c  = gf * sc[tid] + gi * gg;
      sc[tid]  = c;
      float h  = go * tanh_(c);
      sh[tid]  = h;
      u16 hb = f2h(h);
      shp[tid] = hb; scp[tid] = f2h(c);
      sXe[t * 128 + tid] = hb;
    }
    __syncthreads();
  }

  {
    u32 wtp[64];
    const float4* w4 = (const float4*)(dW1 + (size_t)hh * 384 + 256);
    #pragma unroll
    for (int i = 0; i < 32; ++i) {
      float4 v = w4[i];
      wtp[2*i] = pkh2(v.x, v.y); wtp[2*i+1] = pkh2(v.z, v.w);
    }
    float b1v = db1[hh];
    u16 e1out[25];
    #pragma unroll 1
    for (int i = 0; i < 25; ++i) {
      int t = q4 * 25 + i;
      const uint4* xe4 = (const uint4*)(sXe + t * 128);
      float a0 = 0.f, a1 = 0.f;
      #pragma unroll
      for (int k = 0; k < 16; ++k) {
        uint4 xv = xe4[k];
        a0 = dot2h(wtp[4*k+0], xv.x, a0);
        a1 = dot2h(wtp[4*k+1], xv.y, a1);
        a0 = dot2h(wtp[4*k+2], xv.z, a0);
        a1 = dot2h(wtp[4*k+3], xv.w, a1);
      }
      e1out[i] = f2h(a0 + a1 + b1v);
    }
    __syncthreads();
    #pragma unroll 1
    for (int i = 0; i < 25; ++i)
      sxh[(q4 * 25 + i) * 128 + hh] = e1out[i];
  }

  u32 wpkD[64];
  {
    const float4* wr = (const float4*)(dWhh + (size_t)tid * 128);
    #pragma unroll
    for (int i = 0; i < 32; ++i) {
      float4 v = wr[i];
      wpkD[2*i] = pkh2(v.x, v.y); wpkD[2*i+1] = pkh2(v.z, v.w);
    }
  }
  u32 wtpU[32];
  {
    const float4* wu = (const float4*)(dW1 + (size_t)hh * 384 + q4 * 64);
    #pragma unroll
    for (int i = 0; i < 16; ++i) {
      float4 v = wu[i];
      wtpU[2*i] = pkh2(v.x, v.y); wtpU[2*i+1] = pkh2(v.z, v.w);
    }
  }
  float biasD = dbih[tid] + dbhh[tid];
  float wihj  = dWih[tid];
  float w2a   = dW2[lane];
  float w2b   = dW2[lane + 64];
  float fcbv  = fcb[0];
  float fcwv  = (tid < 128) ? fcW[tid] : 0.f;
  if (tid < 128) { sh[tid] = 0.f; sc[tid] = 0.f; shp[tid] = 0; scp[tid] = 0; }
  __syncthreads();

  for (int step = 0; step < T_; ++step) {
    {
      const u32* base = (q4 < 2) ? (const u32*)shp : (const u32*)scp;
      const uint4* vp = (const uint4*)(base + (q4 & 1) * 32);
      float a0 = 0.f, a1 = 0.f;
      #pragma unroll
      for (int k = 0; k < 8; ++k) {
        uint4 v = vp[k];
        a0 = dot2h(wtpU[4*k+0], v.x, a0);
        a1 = dot2h(wtpU[4*k+1], v.y, a1);
        a0 = dot2h(wtpU[4*k+2], v.z, a0);
        a1 = dot2h(wtpU[4*k+3], v.w, a1);
      }
      spart[q4 * 128 + hh] = a0 + a1;
    }
    __syncthreads();
    {
      float ul = spart[lane] + spart[128 + lane]
               + spart[256 + lane] + spart[384 + lane];
      float uh = spart[64 + lane] + spart[192 + lane]
               + spart[320 + lane] + spart[448 + lane];
      #pragma unroll 1
      for (int i = 0; i < 13; ++i) {
        int t = wv + 8 * i;
        if (t < T_) {
          float v = w2a * ptanh(h2f(sxh[t * 128 + lane]) + ul)
                  + w2b * ptanh(h2f(sxh[t * 128 + 64 + lane]) + uh);
          v = wsum(v);
          if (lane == 0) sscore[t] = v;
        }
      }
    }
    __syncthreads();
    if (wv == 0) {
      float s0 = sscore[lane];
      float E0 = __expf(s0);
      float E1v = (lane < 36) ? __expf(sscore[lane + 64]) : 0.f;
      float s  = wsum(E0 + E1v);
      float iv = rcpf_(s);
      sscore[lane] = E0 * iv;
      if (lane < 36) sscore[lane + 64] = E1v * iv;
    }
    __syncthreads();
    {
      float pc = 0.f;
      #pragma unroll
      for (int i = 0; i < 25; ++i) {
        int t = q4 * 25 + i;
        pc += sscore[t] * h2f(sXe[t * 128 + hh]);
      }
      spart[q4 * 128 + hh] = pc;
    }
    __syncthreads();
    {
      float v = 0.f;
      if (tid < 128) {
        float cx = spart[tid] + spart[tid + 128]
                 + spart[tid + 256] + spart[tid + 384];
        sctx[tid] = cx;
        v = fcwv * cx;
      }
      v = wsum(v);
      if (lane == 0 && wv < 2) sredY[wv] = v;
    }
    __syncthreads();
    {
      float yt = sredY[0] + sredY[1] + fcbv;
      float a0 = biasD + wihj * yt, a1 = 0.f, a2 = 0.f, a3 = 0.f;
      const uint4* hr = (const uint4*)(const u32*)shp;
      #pragma unroll
      for (int k = 0; k < 16; ++k) {
        uint4 hv = hr[k];
        a0 = dot2h(wpkD[4*k+0], hv.x, a0);
        a1 = dot2h(wpkD[4*k+1], hv.y, a1);
        a2 = dot2h(wpkD[4*k+2], hv.z, a2);
        a3 = dot2h(wpkD[4*k+3], hv.w, a3);
      }
      sg[tid] = (a0 + a1) + (a2 + a3);
    }
    __syncthreads();
    if (tid < 128) {
      float gi = sigm(sg[tid]);
      float gf = sigm(sg[tid + 128]);
      float gg = tanh_(sg[tid + 256]);
      float go = sigm(sg[tid + 384]);
      float c  = gf * sc[tid] + gi * gg;
      sc[tid]  = c;
      float d  = go * tanh_(c);
      sh[tid]  = d;
      shp[tid] = f2h(d);
      scp[tid] = f2h(c);
    }
    __syncthreads();
  }

  if (tid < C_) {
    float acc = fcfb[tid];
    const float* w = fcfW + (size_t)tid * 256;
    #pragma unroll 8
    for (int k = 0; k < 128; ++k)
      acc += w[k] * sh[k] + w[128 + k] * sctx[k];
    out[(size_t)b * C_ + tid] = acc;
  }
}

extern "C" void kernel_launch(void* const* d_in, const int* in_sizes, int n_in,
                              void* d_out, int out_size, void* d_ws, size_t ws_size,
                              hipStream_t stream) {
  (void)n_in; (void)out_size;
  const float* X    = (const float*)d_in[0];
  const float* eWih = (const float*)d_in[1];
  const float* eWhh = (const float*)d_in[2];
  const float* ebih = (const float*)d_in[3];
  const float* ebhh = (const float*)d_in[4];
  const float* eAw  = (const float*)d_in[5];
  const float* eAb  = (const float*)d_in[6];
  const float* dW1  = (const float*)d_in[7];
  const float* db1  = (const float*)d_in[8];
  const float* dW2  = (const float*)d_in[9];
  const float* db2  = (const float*)d_in[10];
  const float* dWih = (const float*)d_in[11];
  const float* dWhh = (const float*)d_in[12];
  const float* dbih = (const float*)d_in[13];
  const float* dbhh = (const float*)d_in[14];
  const float* fcW  = (const float*)d_in[15];
  const float* fcb  = (const float*)d_in[16];
  const float* fcfW = (const float*)d_in[17];
  const float* fcfb = (const float*)d_in[18];
  float* out = (float*)d_out;

  const int B = in_sizes[0] / (T_ * 128);
  const size_t needQ = (size_t)B * QS * sizeof(u16);
  if (ws_size >= needQ && (B % BPB) == 0) {
    darnn4<<<dim3(B / BPB), dim3(NT), 0, stream>>>(
        X, eWih, eWhh, ebih, ebhh, eAw, eAb,
        dW1, db1, dW2, db2, dWih, dWhh, dbih, dbhh,
        fcW, fcb, fcfW, fcfb, (u16*)d_ws, out);
  } else {
    darnn_fb<<<dim3(B), dim3(NT), 0, stream>>>(
        X, eWih, eWhh, ebih, ebhh, eAw,
        dW1, db1, dW2, dWih, dWhh, dbih, dbhh,
        fcW, fcb, fcfW, fcfb, out);
  }
}

// Round 10
// 648.519 us; speedup vs baseline: 1.7417x; 1.1321x over previous
//
#include <hip/hip_runtime.h>

// DA-RNN fused — R18: Q GEMM + E1 to MFMA; S6 overlapped under S2.
//  * R17 post-mortem: 1126->734, MfmaUtil 8.15%, predictions matched. Largest
//    remaining VALU blocks: S2 tanh (~58K, algorithmic floor), Q GEMM (~20K),
//    S3 (~18K), E1 (~5K). Q/E1 are true GEMMs (N=400=(t,bg) = 25 FULL 16-col
//    MFMA tiles, all lanes used).
//  * R18a: Q GEMM via mfma_16x16x32_f16 (same HW-verified operand convention
//    as R17); C rows contiguous per lane -> uint2 global stores.
//  * R18b: E1 via MFMA; B-frags read Xe from qws (uint4, L2-resident);
//    bias added on C; uint2 ds_write into sE1.
//  * R18c: S6 moved into P2 — reads only prev-state, sg consumed in P3, so
//    its MFMAs retire under S2's VALU stream. P1 = S0 only.
//  * launch_bounds(512,1): occupancy is LDS-bound (1 block/CU); VGPR may grow
//    past 128 without cost — avoid the compiler's 128-cap spill.

typedef unsigned int   u32;
typedef unsigned short u16;

#define T_  100
#define C_  32
#define NT  512
#define BPB 4
#define TS  132
#define QS  (T_ * NT)
#define SP  160   // shp/scp padded row (u16)

typedef __attribute__((ext_vector_type(2))) __fp16 h16x2;
typedef __attribute__((ext_vector_type(8))) __fp16 h16x8;
typedef __attribute__((ext_vector_type(4))) float  f32x4;

#if __has_builtin(__builtin_amdgcn_fdot2)
#define HAVE_FDOT2 1
#else
#define HAVE_FDOT2 0
#endif

__device__ __forceinline__ u32 pkh2(float a, float b) {
#if __has_builtin(__builtin_amdgcn_cvt_pkrtz)
  h16x2 p = __builtin_amdgcn_cvt_pkrtz(a, b);
  return __builtin_bit_cast(u32, p);
#else
  union { __fp16 h[2]; u32 u; } v;
  v.h[0] = (__fp16)a; v.h[1] = (__fp16)b;
  return v.u;
#endif
}
__device__ __forceinline__ void unph(u32 p, float& lo, float& hi) {
  union { u32 u; __fp16 h[2]; } v; v.u = p;
  lo = (float)v.h[0]; hi = (float)v.h[1];
}
__device__ __forceinline__ u16 f2h(float f) {
  union { __fp16 h; u16 u; } v; v.h = (__fp16)f; return v.u;
}
__device__ __forceinline__ float h2f(u16 u) {
  union { u16 u; __fp16 h; } v; v.u = u; return (float)v.h;
}
__device__ __forceinline__ float dot2h(u32 w, u32 x, float acc) {
#if HAVE_FDOT2
  return __builtin_amdgcn_fdot2(__builtin_bit_cast(h16x2, w),
                                __builtin_bit_cast(h16x2, x),
                                acc, false);
#else
  float a, b, c, d;
  unph(w, a, b); unph(x, c, d);
  return fmaf(a, c, fmaf(b, d, acc));
#endif
}
// pack 8 consecutive floats at p into 8 fp16 (A-fragment)
__device__ __forceinline__ h16x8 pack8(const float* p) {
  float4 v0 = *(const float4*)p;
  float4 v1 = *(const float4*)(p + 4);
  uint4 u;
  u.x = pkh2(v0.x, v0.y); u.y = pkh2(v0.z, v0.w);
  u.z = pkh2(v1.x, v1.y); u.w = pkh2(v1.z, v1.w);
  return __builtin_bit_cast(h16x8, u);
}
// load 8 consecutive fp16 (B-fragment) — LDS or global
__device__ __forceinline__ h16x8 ldb(const u16* p, int off) {
  return __builtin_bit_cast(h16x8, *(const uint4*)(p + off));
}

#if __has_builtin(__builtin_amdgcn_rcpf)
__device__ __forceinline__ float rcpf_(float x){ return __builtin_amdgcn_rcpf(x); }
#else
__device__ __forceinline__ float rcpf_(float x){ return 1.0f / x; }
#endif
__device__ __forceinline__ float sigm(float x){ return rcpf_(1.0f + __expf(-x)); }
__device__ __forceinline__ float tanh_(float x){
  return 1.0f - 2.0f * rcpf_(1.0f + __expf(2.0f * x));
}
// packed-fp16 tanh approx of (e+u), both packed half2 as u32
__device__ __forceinline__ u32 tanhpk(u32 eu, u32 uu) {
  h16x2 x = __builtin_bit_cast(h16x2, eu) + __builtin_bit_cast(h16x2, uu);
  const h16x2 one  = {(__fp16)1.0f,  (__fp16)1.0f};
#if __has_builtin(__builtin_elementwise_max) && __has_builtin(__builtin_elementwise_min)
  const h16x2 mone = {(__fp16)-1.0f, (__fp16)-1.0f};
  x = __builtin_elementwise_min(one, __builtin_elementwise_max(x, mone));
#else
  {
    float lo, hi; unph(__builtin_bit_cast(u32, x), lo, hi);
    x = (h16x2){(__fp16)fminf(1.f, fmaxf(-1.f, lo)),
                (__fp16)fminf(1.f, fmaxf(-1.f, hi))};
  }
#endif
  h16x2 x2 = x * x;
  const h16x2 c1 = {(__fp16)0.1333333f,  (__fp16)0.1333333f};
  const h16x2 c0 = {(__fp16)-0.3333333f, (__fp16)-0.3333333f};
  h16x2 r = x * (x2 * (x2 * c1 + c0) + one);
  return __builtin_bit_cast(u32, r);
}
__device__ __forceinline__ float ptanh(float x){
  x = fminf(1.0f, fmaxf(-1.0f, x));
  float x2 = x * x;
  float p  = fmaf(x2, 0.1333333f, -0.3333333f);
  return x * fmaf(x2, p, 1.0f);
}
__device__ __forceinline__ float wsum(float v){
  #pragma unroll
  for (int o = 32; o; o >>= 1) v += __shfl_xor(v, o, 64);
  return v;
}

// ============================ fast kernel (4 batches/block) =================
__global__ void __launch_bounds__(NT, 1)
darnn4(const float* __restrict__ X,
       const float* __restrict__ eWih, const float* __restrict__ eWhh,
       const float* __restrict__ ebih, const float* __restrict__ ebhh,
       const float* __restrict__ eAw,  const float* __restrict__ eAb,
       const float* __restrict__ dW1,  const float* __restrict__ db1,
       const float* __restrict__ dW2,  const float* __restrict__ db2,
       const float* __restrict__ dWih, const float* __restrict__ dWhh,
       const float* __restrict__ dbih, const float* __restrict__ dbhh,
       const float* __restrict__ fcW,  const float* __restrict__ fcb,
       const float* __restrict__ fcfW, const float* __restrict__ fcfb,
       u16* __restrict__ qws,
       float* __restrict__ out)
{
  // LDS ~131.1 KB
  __shared__ __align__(16) u16   sE1[BPB][T_ * TS];  // x_tilde -> E1   105600
  __shared__ __align__(16) float sg[BPB][520];       // gates (padded)   8320
  __shared__ __align__(16) float sh[BPB][128];       // h/d fp32         2048
  __shared__ __align__(16) float sc[BPB][128];       // c fp32           2048
  __shared__ __align__(16) u16   shp[BPB][SP];       // h/d fp16 (pad)   1280
  __shared__ __align__(16) u16   scp[BPB][SP];       // c fp16 (pad)     1280
  __shared__ __align__(16) float su[BPB][128];       // ctx              2048
  __shared__ __align__(16) float spart[BPB][512];    // partials         8192
  __shared__ __align__(16) float sye[BPB][128];      // ye -> beta       2048
  __shared__ __align__(16) u32   su2[BPB][68];       // packed u (pad)   1088
  __shared__ __align__(16) u32   sw2p[64];           // packed w2         256
  __shared__ float sred[16];

  const int tid  = threadIdx.x;
  const int lane = tid & 63;
  const int wv   = tid >> 6;     // 0..7
  const int hh   = tid & 127;
  const int q4   = tid >> 7;     // 0..3
  const int nn   = lane & 15;    // MFMA col
  const int kg   = lane >> 4;    // MFMA k-group
  const bool wr  = (nn < BPB);   // gate-MFMA result lanes
  const int tq   = nn >> 2;      // t offset within 16-col (t,bg) tile
  const int bq   = nn & 3;       // batch within tile
  const int b0   = blockIdx.x * BPB;

  (void)eAb; (void)db2;          // cancel under softmax shift-invariance

  if (tid < 64) sw2p[tid] = pkh2(dW2[2 * tid], dW2[2 * tid + 1]);

  // ---------- alpha (no max-sub; h/c terms cancel) + x_tilde ----------
  {
    const float* xp = X + (size_t)(b0 + q4) * 12800 + hh;
    float sval = 0.f;
    #pragma unroll 4
    for (int t = 0; t < T_; ++t) sval += xp[t * 128] * eAw[256 + t];
    float e = __expf(sval);
    float s = wsum(e);
    if (lane == 0) sred[wv] = s;
    __syncthreads();
    float al = e * rcpf_(sred[q4 * 2] + sred[q4 * 2 + 1]);
    #pragma unroll 4
    for (int t = 0; t < T_; ++t)
      sE1[q4][t * TS + hh] = f2h(al * xp[t * 128]);
    sh[q4][hh] = 0.f; sc[q4][hh] = 0.f; shp[q4][hh] = 0; scp[q4][hh] = 0;
  }
  __syncthreads();

  // ---------- Q GEMM via MFMA: Q[b][t][r] = eWih[r,:]·x_tilde ----------
  // M=512 (8 waves x 4 row-tiles), K=128 (4 ks), N=400 (25 tiles of 4t x 4bg;
  // ALL 16 cols used). C rows contiguous per lane -> uint2 global stores.
  {
    h16x8 aQ[16];
    #pragma unroll
    for (int mt = 0; mt < 4; ++mt)
      #pragma unroll
      for (int ks = 0; ks < 4; ++ks)
        aQ[mt*4+ks] = pack8(eWih + (size_t)(wv*64 + mt*16 + nn) * 128
                            + ks*32 + kg*8);
    #pragma unroll 1
    for (int tn = 0; tn < 25; ++tn) {
      const int t = tn * 4 + tq;
      const u16* xb = &sE1[bq][t * TS];
      f32x4 c0={0,0,0,0}, c1={0,0,0,0}, c2={0,0,0,0}, c3={0,0,0,0};
      #pragma unroll
      for (int ks = 0; ks < 4; ++ks) {
        h16x8 b = ldb(xb, ks*32 + kg*8);
        c0 = __builtin_amdgcn_mfma_f32_16x16x32_f16(aQ[0*4+ks], b, c0, 0,0,0);
        c1 = __builtin_amdgcn_mfma_f32_16x16x32_f16(aQ[1*4+ks], b, c1, 0,0,0);
        c2 = __builtin_amdgcn_mfma_f32_16x16x32_f16(aQ[2*4+ks], b, c2, 0,0,0);
        c3 = __builtin_amdgcn_mfma_f32_16x16x32_f16(aQ[3*4+ks], b, c3, 0,0,0);
      }
      u16* qb = qws + (size_t)(b0 + bq) * QS + (size_t)t * NT + wv*64 + kg*4;
      uint2 p;
      p.x = pkh2(c0[0], c0[1]); p.y = pkh2(c0[2], c0[3]); *(uint2*)(qb)      = p;
      p.x = pkh2(c1[0], c1[1]); p.y = pkh2(c1[2], c1[3]); *(uint2*)(qb + 16) = p;
      p.x = pkh2(c2[0], c2[1]); p.y = pkh2(c2[2], c2[3]); *(uint2*)(qb + 32) = p;
      p.x = pkh2(c3[0], c3[1]); p.y = pkh2(c3[2], c3[3]); *(uint2*)(qb + 48) = p;
    }
  }
  __syncthreads();   // Q consumed cross-thread by encoder

  // ---------- encoder (MFMA gates; 2 barriers/step) ----------
  {
    h16x8 aH[16];
    #pragma unroll
    for (int rt = 0; rt < 4; ++rt)
      #pragma unroll
      for (int ks = 0; ks < 4; ++ks)
        aH[rt*4+ks] = pack8(eWhh + (size_t)(wv*64 + rt*16 + nn) * 128
                            + ks*32 + kg*8);
    float bgx = ebih[hh]       + ebhh[hh];
    float bgy = ebih[hh + 128] + ebhh[hh + 128];
    float bgz = ebih[hh + 256] + ebhh[hh + 256];
    float bgw = ebih[hh + 384] + ebhh[hh + 384];
    const u16* qrow = qws + (size_t)(b0 + q4) * QS + hh;

    for (int t = 0; t < T_; ++t) {
      u16 qv0 = qrow[t * NT];
      u16 qv1 = qrow[t * NT + 128];
      u16 qv2 = qrow[t * NT + 256];
      u16 qv3 = qrow[t * NT + 384];
      f32x4 g0 = {0,0,0,0}, g1 = {0,0,0,0}, g2 = {0,0,0,0}, g3 = {0,0,0,0};
      #pragma unroll
      for (int ks = 0; ks < 4; ++ks) {
        h16x8 b = ldb(&shp[nn & 3][0], ks*32 + kg*8);
        g0 = __builtin_amdgcn_mfma_f32_16x16x32_f16(aH[0*4+ks], b, g0, 0,0,0);
        g1 = __builtin_amdgcn_mfma_f32_16x16x32_f16(aH[1*4+ks], b, g1, 0,0,0);
        g2 = __builtin_amdgcn_mfma_f32_16x16x32_f16(aH[2*4+ks], b, g2, 0,0,0);
        g3 = __builtin_amdgcn_mfma_f32_16x16x32_f16(aH[3*4+ks], b, g3, 0,0,0);
      }
      if (wr) {
        *(f32x4*)(&sg[nn][wv*64 +  0 + kg*4]) = g0;
        *(f32x4*)(&sg[nn][wv*64 + 16 + kg*4]) = g1;
        *(f32x4*)(&sg[nn][wv*64 + 32 + kg*4]) = g2;
        *(f32x4*)(&sg[nn][wv*64 + 48 + kg*4]) = g3;
      }
      __syncthreads();
      {
        float gi = sigm (sg[q4][hh]       + bgx + h2f(qv0));
        float gf = sigm (sg[q4][hh + 128] + bgy + h2f(qv1));
        float gg = tanh_(sg[q4][hh + 256] + bgz + h2f(qv2));
        float go = sigm (sg[q4][hh + 384] + bgw + h2f(qv3));
        float c  = gf * sc[q4][hh] + gi * gg;
        sc[q4][hh] = c;
        float h  = go * tanh_(c);
        sh[q4][hh] = h;
        u16 hb = f2h(h);
        shp[q4][hh] = hb;
        scp[q4][hh] = f2h(c);
        // Xe row t shares Q's slab (Q[t] consumed pre-barrier; reg-held)
        qws[(size_t)(b0 + q4) * QS + t * NT + hh] = hb;
      }
      __syncthreads();
    }
  }

  // ---------- ye[t] = fcW · Xe[t]  ----------
  if (hh < T_) {
    #pragma unroll 1
    for (int bg = 0; bg < BPB; ++bg) {
      const uint2* xe = (const uint2*)(qws + (size_t)(b0 + bg) * QS
                                       + hh * NT + q4 * 32);
      const float* fw = fcW + q4 * 32;
      float a = 0.f;
      #pragma unroll
      for (int k = 0; k < 8; ++k) {
        uint2 xv = xe[k];
        float l0, l1, l2, l3;
        unph(xv.x, l0, l1); unph(xv.y, l2, l3);
        a += fw[4*k]*l0 + fw[4*k+1]*l1 + fw[4*k+2]*l2 + fw[4*k+3]*l3;
      }
      spart[bg][hh * 4 + q4] = a;
    }
  }
  __syncthreads();
  if (hh < T_) {
    float4 p = ((const float4*)spart[q4])[hh];
    sye[q4][hh] = (p.x + p.y) + (p.z + p.w);
  }
  __syncthreads();

  // ---------- E1 via MFMA: E1[t][h] = dW1[h][256:384]·Xe[t] + db1[h] ------
  // M=128 (8 waves x 1 row-tile), K=128, N=400; B-frags from qws (L2).
  {
    h16x8 aE[4];
    #pragma unroll
    for (int ks = 0; ks < 4; ++ks)
      aE[ks] = pack8(dW1 + (size_t)(wv*16 + nn) * 384 + 256 + ks*32 + kg*8);
    float4 b1 = *(const float4*)(db1 + wv*16 + kg*4);
    #pragma unroll 1
    for (int tn = 0; tn < 25; ++tn) {
      const int t = tn * 4 + tq;
      const u16* xb = qws + (size_t)(b0 + bq) * QS + (size_t)t * NT;
      f32x4 c = {0,0,0,0};
      #pragma unroll
      for (int ks = 0; ks < 4; ++ks) {
        h16x8 b = ldb(xb, ks*32 + kg*8);
        c = __builtin_amdgcn_mfma_f32_16x16x32_f16(aE[ks], b, c, 0,0,0);
      }
      uint2 p;
      p.x = pkh2(c[0] + b1.x, c[1] + b1.y);
      p.y = pkh2(c[2] + b1.z, c[3] + b1.w);
      *(uint2*)(&sE1[bq][t * TS + wv*16 + kg*4]) = p;
    }
  }

  // ---------- decoder weights (MFMA A-fragments) ----------
  h16x8 aD[16];   // dWhh rows [wv*64, +64)
  #pragma unroll
  for (int rt = 0; rt < 4; ++rt)
    #pragma unroll
    for (int ks = 0; ks < 4; ++ks)
      aD[rt*4+ks] = pack8(dWhh + (size_t)(wv*64 + rt*16 + nn) * 128
                          + ks*32 + kg*8);
  h16x8 aU[8];    // dW1 z-part rows [wv*16, +16), cols 0..255
  #pragma unroll
  for (int ks = 0; ks < 8; ++ks)
    aU[ks] = pack8(dW1 + (size_t)(wv*16 + nn) * 384 + ks*32 + kg*8);
  float bdx = dbih[hh]       + dbhh[hh];
  float bdy = dbih[hh + 128] + dbhh[hh + 128];
  float bdz = dbih[hh + 256] + dbhh[hh + 256];
  float bdw = dbih[hh + 384] + dbhh[hh + 384];
  float wix = dWih[hh];
  float wiy = dWih[hh + 128];
  float wiz = dWih[hh + 256];
  float wiw = dWih[hh + 384];
  float fcbv = fcb[0];
  sh[q4][hh] = 0.f; sc[q4][hh] = 0.f; shp[q4][hh] = 0; scp[q4][hh] = 0;
  __syncthreads();

  // ---------- decoder (3 barriers/step) ----------
  for (int step = 0; step < T_; ++step) {
    // P1 (S0, MFMA): u = dW1z · [d;c]; wave wv owns u-rows [wv*16,+16)
    {
      f32x4 au = {0,0,0,0};
      #pragma unroll
      for (int ks = 0; ks < 8; ++ks) {
        const u16* bp = (ks < 4) ? &shp[nn & 3][0] : &scp[nn & 3][0];
        h16x8 b = ldb(bp, (ks & 3)*32 + kg*8);
        au = __builtin_amdgcn_mfma_f32_16x16x32_f16(aU[ks], b, au, 0,0,0);
      }
      if (wr) {
        uint2 up;
        up.x = pkh2(au[0], au[1]);
        up.y = pkh2(au[2], au[3]);
        *(uint2*)(&su2[nn][wv*8 + kg*2]) = up;
      }
    }
    __syncthreads();
    // P2 (S6 MFMA overlapped under S2 VALU)
    f32x4 g0 = {0,0,0,0}, g1 = {0,0,0,0}, g2 = {0,0,0,0}, g3 = {0,0,0,0};
    #pragma unroll
    for (int ks = 0; ks < 4; ++ks) {
      h16x8 b = ldb(&shp[nn & 3][0], ks*32 + kg*8);
      g0 = __builtin_amdgcn_mfma_f32_16x16x32_f16(aD[0*4+ks], b, g0, 0,0,0);
      g1 = __builtin_amdgcn_mfma_f32_16x16x32_f16(aD[1*4+ks], b, g1, 0,0,0);
      g2 = __builtin_amdgcn_mfma_f32_16x16x32_f16(aD[2*4+ks], b, g2, 0,0,0);
      g3 = __builtin_amdgcn_mfma_f32_16x16x32_f16(aD[3*4+ks], b, g3, 0,0,0);
    }
    // S2: score partials, packed fp16: thread (t=hh<100, q4), 32 h each
    if (hh < T_) {
      const uint2* wp  = (const uint2*)(sw2p + q4 * 16);
      const uint2* e0p = (const uint2*)(&sE1[0][hh * TS + q4 * 32]);
      const uint2* e1p = (const uint2*)(&sE1[1][hh * TS + q4 * 32]);
      const uint2* e2p = (const uint2*)(&sE1[2][hh * TS + q4 * 32]);
      const uint2* e3p = (const uint2*)(&sE1[3][hh * TS + q4 * 32]);
      const uint2* u0p = (const uint2*)(su2[0] + q4 * 16);
      const uint2* u1p = (const uint2*)(su2[1] + q4 * 16);
      const uint2* u2p = (const uint2*)(su2[2] + q4 * 16);
      const uint2* u3p = (const uint2*)(su2[3] + q4 * 16);
      float ac0 = 0.f, ac1 = 0.f, ac2 = 0.f, ac3 = 0.f;
      #pragma unroll
      for (int j = 0; j < 8; ++j) {
        uint2 w2v = wp[j];
        uint2 ev, uv;
        ev = e0p[j]; uv = u0p[j];
        ac0 = dot2h(w2v.x, tanhpk(ev.x, uv.x), ac0);
        ac0 = dot2h(w2v.y, tanhpk(ev.y, uv.y), ac0);
        ev = e1p[j]; uv = u1p[j];
        ac1 = dot2h(w2v.x, tanhpk(ev.x, uv.x), ac1);
        ac1 = dot2h(w2v.y, tanhpk(ev.y, uv.y), ac1);
        ev = e2p[j]; uv = u2p[j];
        ac2 = dot2h(w2v.x, tanhpk(ev.x, uv.x), ac2);
        ac2 = dot2h(w2v.y, tanhpk(ev.y, uv.y), ac2);
        ev = e3p[j]; uv = u3p[j];
        ac3 = dot2h(w2v.x, tanhpk(ev.x, uv.x), ac3);
        ac3 = dot2h(w2v.y, tanhpk(ev.y, uv.y), ac3);
      }
      spart[0][hh * 4 + q4] = ac0;
      spart[1][hh * 4 + q4] = ac1;
      spart[2][hh * 4 + q4] = ac2;
      spart[3][hh * 4 + q4] = ac3;
    }
    if (wr) {
      *(f32x4*)(&sg[nn][wv*64 +  0 + kg*4]) = g0;
      *(f32x4*)(&sg[nn][wv*64 + 16 + kg*4]) = g1;
      *(f32x4*)(&sg[nn][wv*64 + 32 + kg*4]) = g2;
      *(f32x4*)(&sg[nn][wv*64 + 48 + kg*4]) = g3;
    }
    __syncthreads();
    // P3 (S3+S7): softmax + y for own quad; pointwise LSTM with bias+y inject
    {
      float yv;
      {
        const int bg = q4;
        float4 p0 = ((const float4*)spart[bg])[lane];
        float e0 = __expf((p0.x + p0.y) + (p0.z + p0.w));
        float es = e0, ys = e0 * sye[bg][lane];
        if (lane < 36) {
          float4 p1 = ((const float4*)spart[bg])[64 + lane];
          float e1 = __expf((p1.x + p1.y) + (p1.z + p1.w));
          es += e1; ys += e1 * sye[bg][64 + lane];
        }
        es = wsum(es); ys = wsum(ys);
        yv = ys * rcpf_(es) + fcbv;
      }
      float gi = sigm (sg[q4][hh]       + bdx + wix * yv);
      float gf = sigm (sg[q4][hh + 128] + bdy + wiy * yv);
      float gg = tanh_(sg[q4][hh + 256] + bdz + wiz * yv);
      float go = sigm (sg[q4][hh + 384] + bdw + wiw * yv);
      float c  = gf * sc[q4][hh] + gi * gg;
      sc[q4][hh] = c;
      float d  = go * tanh_(c);
      sh[q4][hh] = d;
      shp[q4][hh] = f2h(d);
      scp[q4][hh] = f2h(c);
    }
    __syncthreads();
  }

  // ---------- final beta -> ctx -> head ----------
  if (wv < BPB) {                     // wave w computes beta for batch w
    int bg = wv;
    float4 p0 = ((const float4*)spart[bg])[lane];
    float e0 = __expf((p0.x + p0.y) + (p0.z + p0.w));
    float e1 = 0.f;
    if (lane < 36) {
      float4 p1 = ((const float4*)spart[bg])[64 + lane];
      e1 = __expf((p1.x + p1.y) + (p1.z + p1.w));
    }
    float iv = rcpf_(wsum(e0 + e1));
    sye[bg][lane] = e0 * iv;          // overwrite ye with beta
    if (lane < 36) sye[bg][64 + lane] = e1 * iv;
  }
  __syncthreads();
  {
    const u16* xeb = qws + (size_t)(b0 + q4) * QS + hh;
    float cx = 0.f;
    #pragma unroll 4
    for (int t = 0; t < T_; ++t)
      cx += sye[q4][t] * h2f(xeb[t * NT]);
    su[q4][hh] = cx;                  // ctx
  }
  __syncthreads();
  if (tid < BPB * C_) {
    int bg = tid >> 5, cls = tid & 31;
    const float* w = fcfW + (size_t)cls * 256;
    float acc = fcfb[cls];
    #pragma unroll 8
    for (int k = 0; k < 128; ++k)
      acc += w[k] * sh[bg][k] + w[128 + k] * su[bg][k];
    out[(size_t)(b0 + bg) * C_ + cls] = acc;
  }
}

// ================== fallback (R7 structure, no workspace) ==================
__global__ void __launch_bounds__(NT)
darnn_fb(const float* __restrict__ X,
         const float* __restrict__ eWih, const float* __restrict__ eWhh,
         const float* __restrict__ ebih, const float* __restrict__ ebhh,
         const float* __restrict__ eAw,
         const float* __restrict__ dW1,  const float* __restrict__ db1,
         const float* __restrict__ dW2,
         const float* __restrict__ dWih, const float* __restrict__ dWhh,
         const float* __restrict__ dbih, const float* __restrict__ dbhh,
         const float* __restrict__ fcW,  const float* __restrict__ fcb,
         const float* __restrict__ fcfW, const float* __restrict__ fcfb,
         float* __restrict__ out)
{
  __shared__ __align__(16) u16   sxh[12800];
  __shared__ __align__(16) u16   sXe[12800];
  __shared__ __align__(16) float sg[512];
  __shared__ __align__(16) float sh[128];
  __shared__ __align__(16) float sc[128];
  __shared__ __align__(16) u16   shp[128];
  __shared__ __align__(16) u16   scp[128];
  __shared__ __align__(16) float su[128];
  __shared__ __align__(16) float spart[512];
  __shared__ __align__(16) float sscore[128];
  __shared__ __align__(16) float sctx[128];
  __shared__ float sred[8];
  __shared__ float sredY[2];

  const int tid  = threadIdx.x;
  const int lane = tid & 63;
  const int wv   = tid >> 6;
  const int b    = blockIdx.x;
  const int hh   = tid & 127;
  const int q4   = tid >> 7;

  {
    const float4* Xb4 = (const float4*)(X + (size_t)b * 12800);
    u32* dst = (u32*)sxh;
    #pragma unroll
    for (int i = 0; i < 7; ++i) {
      int idx = tid + NT * i;
      if (idx < 3200) {
        float4 v = Xb4[idx];
        dst[2*idx]   = pkh2(v.x, v.y);
        dst[2*idx+1] = pkh2(v.z, v.w);
      }
    }
  }
  __syncthreads();
  float sval = 0.f;
  if (tid < 128) {
    #pragma unroll 4
    for (int t = 0; t < T_; ++t)
      sval += h2f(sxh[t * 128 + tid]) * eAw[256 + t];
  }
  float ee = (tid < 128) ? __expf(sval) : 0.f;
  float sm = wsum(ee);
  if (lane == 0 && wv < 2) sred[2 + wv] = sm;
  __syncthreads();
  if (tid < 128) {
    su[tid] = ee * rcpf_(sred[2] + sred[3]);
    sh[tid] = 0.f; sc[tid] = 0.f; shp[tid] = 0; scp[tid] = 0;
  }
  __syncthreads();
  {
    u32* sx32 = (u32*)sxh;
    #pragma unroll
    for (int i = 0; i < 13; ++i) {
      int p = tid + NT * i;
      if (p < 6400) {
        float lo, hi; unph(sx32[p], lo, hi);
        int m = (2 * p) & 127;
        sx32[p] = pkh2(lo * su[m], hi * su[m + 1]);
      }
    }
  }
  __syncthreads();

  u32 wpkH[64], wpkI[64];
  {
    const float4* wr = (const float4*)(eWhh + (size_t)tid * 128);
    #pragma unroll
    for (int i = 0; i < 32; ++i) {
      float4 v = wr[i];
      wpkH[2*i] = pkh2(v.x, v.y); wpkH[2*i+1] = pkh2(v.z, v.w);
    }
    const float4* wi = (const float4*)(eWih + (size_t)tid * 128);
    #pragma unroll
    for (int i = 0; i < 32; ++i) {
      float4 v = wi[i];
      wpkI[2*i] = pkh2(v.x, v.y); wpkI[2*i+1] = pkh2(v.z, v.w);
    }
  }
  float biasg = ebih[tid] + ebhh[tid];

  for (int t = 0; t < T_; ++t) {
    float a0 = biasg, a1 = 0.f, a2 = 0.f, a3 = 0.f;
    const uint4* hr = (const uint4*)(const u32*)shp;
    #pragma unroll
    for (int k = 0; k < 16; ++k) {
      uint4 hv = hr[k];
      a0 = dot2h(wpkH[4*k+0], hv.x, a0);
      a1 = dot2h(wpkH[4*k+1], hv.y, a1);
      a2 = dot2h(wpkH[4*k+2], hv.z, a2);
      a3 = dot2h(wpkH[4*k+3], hv.w, a3);
    }
    const uint4* xr = (const uint4*)((const u32*)sxh + t * 64);
    #pragma unroll
    for (int k = 0; k < 16; ++k) {
      uint4 xv = xr[k];
      a0 = dot2h(wpkI[4*k+0], xv.x, a0);
      a1 = dot2h(wpkI[4*k+1], xv.y, a1);
      a2 = dot2h(wpkI[4*k+2], xv.z, a2);
      a3 = dot2h(wpkI[4*k+3], xv.w, a3);
    }
    sg[tid] = (a0 + a1) + (a2 + a3);
    __syncthreads();
    if (tid < 128) {
      float gi = sigm(sg[tid]);
      float gf = sigm(sg[tid + 128]);
      float gg = tanh_(sg[tid + 256]);
      float go = sigm(sg[tid + 384]);
      float c  = gf * sc[tid] + gi * gg;
      sc[tid]  = c;
      float h  = go * tanh_(c);
      sh[tid]  = h;
      u16 hb = f2h(h);
      shp[tid] = hb; scp[tid] = f2h(c);
      sXe[t * 128 + tid] = hb;
    }
    __syncthreads();
  }

  {
    u32 wtp[64];
    const float4* w4 = (const float4*)(dW1 + (size_t)hh * 384 + 256);
    #pragma unroll
    for (int i = 0; i < 32; ++i) {
      float4 v = w4[i];
      wtp[2*i] = pkh2(v.x, v.y); wtp[2*i+1] = pkh2(v.z, v.w);
    }
    float b1v = db1[hh];
    u16 e1out[25];
    #pragma unroll 1
    for (int i = 0; i < 25; ++i) {
      int t = q4 * 25 + i;
      const uint4* xe4 = (const uint4*)(sXe + t * 128);
      float a0 = 0.f, a1 = 0.f;
      #pragma unroll
      for (int k = 0; k < 16; ++k) {
        uint4 xv = xe4[k];
        a0 = dot2h(wtp[4*k+0], xv.x, a0);
        a1 = dot2h(wtp[4*k+1], xv.y, a1);
        a0 = dot2h(wtp[4*k+2], xv.z, a0);
        a1 = dot2h(wtp[4*k+3], xv.w, a1);
      }
      e1out[i] = f2h(a0 + a1 + b1v);
    }
    __syncthreads();
    #pragma unroll 1
    for (int i = 0; i < 25; ++i)
      sxh[(q4 * 25 + i) * 128 + hh] = e1out[i];
  }

  u32 wpkD[64];
  {
    const float4* wr = (const float4*)(dWhh + (size_t)tid * 128);
    #pragma unroll
    for (int i = 0; i < 32; ++i) {
      float4 v = wr[i];
      wpkD[2*i] = pkh2(v.x, v.y); wpkD[2*i+1] = pkh2(v.z, v.w);
    }
  }
  u32 wtpU[32];
  {
    const float4* wu = (const float4*)(dW1 + (size_t)hh * 384 + q4 * 64);
    #pragma unroll
    for (int i = 0; i < 16; ++i) {
      float4 v = wu[i];
      wtpU[2*i] = pkh2(v.x, v.y); wtpU[2*i+1] = pkh2(v.z, v.w);
    }
  }
  float biasD = dbih[tid] + dbhh[tid];
  float wihj  = dWih[tid];
  float w2a   = dW2[lane];
  float w2b   = dW2[lane + 64];
  float fcbv  = fcb[0];
  float fcwv  = (tid < 128) ? fcW[tid] : 0.f;
  if (tid < 128) { sh[tid] = 0.f; sc[tid] = 0.f; shp[tid] = 0; scp[tid] = 0; }
  __syncthreads();

  for (int step = 0; step < T_; ++step) {
    {
      const u32* base = (q4 < 2) ? (const u32*)shp : (const u32*)scp;
      const uint4* vp = (const uint4*)(base + (q4 & 1) * 32);
      float a0 = 0.f, a1 = 0.f;
      #pragma unroll
      for (int k = 0; k < 8; ++k) {
        uint4 v = vp[k];
        a0 = dot2h(wtpU[4*k+0], v.x, a0);
        a1 = dot2h(wtpU[4*k+1], v.y, a1);
        a0 = dot2h(wtpU[4*k+2], v.z, a0);
        a1 = dot2h(wtpU[4*k+3], v.w, a1);
      }
      spart[q4 * 128 + hh] = a0 + a1;
    }
    __syncthreads();
    {
      float ul = spart[lane] + spart[128 + lane]
               + spart[256 + lane] + spart[384 + lane];
      float uh = spart[64 + lane] + spart[192 + lane]
               + spart[320 + lane] + spart[448 + lane];
      #pragma unroll 1
      for (int i = 0; i < 13; ++i) {
        int t = wv + 8 * i;
        if (t < T_) {
          float v = w2a * ptanh(h2f(sxh[t * 128 + lane]) + ul)
                  + w2b * ptanh(h2f(sxh[t * 128 + 64 + lane]) + uh);
          v = wsum(v);
          if (lane == 0) sscore[t] = v;
        }
      }
    }
    __syncthreads();
    if (wv == 0) {
      float s0 = sscore[lane];
      float E0 = __expf(s0);
      float E1v = (lane < 36) ? __expf(sscore[lane + 64]) : 0.f;
      float s  = wsum(E0 + E1v);
      float iv = rcpf_(s);
      sscore[lane] = E0 * iv;
      if (lane < 36) sscore[lane + 64] = E1v * iv;
    }
    __syncthreads();
    {
      float pc = 0.f;
      #pragma unroll
      for (int i = 0; i < 25; ++i) {
        int t = q4 * 25 + i;
        pc += sscore[t] * h2f(sXe[t * 128 + hh]);
      }
      spart[q4 * 128 + hh] = pc;
    }
    __syncthreads();
    {
      float v = 0.f;
      if (tid < 128) {
        float cx = spart[tid] + spart[tid + 128]
                 + spart[tid + 256] + spart[tid + 384];
        sctx[tid] = cx;
        v = fcwv * cx;
      }
      v = wsum(v);
      if (lane == 0 && wv < 2) sredY[wv] = v;
    }
    __syncthreads();
    {
      float yt = sredY[0] + sredY[1] + fcbv;
      float a0 = biasD + wihj * yt, a1 = 0.f, a2 = 0.f, a3 = 0.f;
      const uint4* hr = (const uint4*)(const u32*)shp;
      #pragma unroll
      for (int k = 0; k < 16; ++k) {
        uint4 hv = hr[k];
        a0 = dot2h(wpkD[4*k+0], hv.x, a0);
        a1 = dot2h(wpkD[4*k+1], hv.y, a1);
        a2 = dot2h(wpkD[4*k+2], hv.z, a2);
        a3 = dot2h(wpkD[4*k+3], hv.w, a3);
      }
      sg[tid] = (a0 + a1) + (a2 + a3);
    }
    __syncthreads();
    if (tid < 128) {
      float gi = sigm(sg[tid]);
      float gf = sigm(sg[tid + 128]);
      float gg = tanh_(sg[tid + 256]);
      float go = sigm(sg[tid + 384]);
      float c  = gf * sc[tid] + gi * gg;
      sc[tid]  = c;
      float d  = go * tanh_(c);
      sh[tid]  = d;
      shp[tid] = f2h(d);
      scp[tid] = f2h(c);
    }
    __syncthreads();
  }

  if (tid < C_) {
    float acc = fcfb[tid];
    const float* w = fcfW + (size_t)tid * 256;
    #pragma unroll 8
    for (int k = 0; k < 128; ++k)
      acc += w[k] * sh[k] + w[128 + k] * sctx[k];
    out[(size_t)b * C_ + tid] = acc;
  }
}

extern "C" void kernel_launch(void* const* d_in, const int* in_sizes, int n_in,
                              void* d_out, int out_size, void* d_ws, size_t ws_size,
                              hipStream_t stream) {
  (void)n_in; (void)out_size;
  const float* X    = (const float*)d_in[0];
  const float* eWih = (const float*)d_in[1];
  const float* eWhh = (const float*)d_in[2];
  const float* ebih = (const float*)d_in[3];
  const float* ebhh = (const float*)d_in[4];
  const float* eAw  = (const float*)d_in[5];
  const float* eAb  = (const float*)d_in[6];
  const float* dW1  = (const float*)d_in[7];
  const float* db1  = (const float*)d_in[8];
  const float* dW2  = (const float*)d_in[9];
  const float* db2  = (const float*)d_in[10];
  const float* dWih = (const float*)d_in[11];
  const float* dWhh = (const float*)d_in[12];
  const float* dbih = (const float*)d_in[13];
  const float* dbhh = (const float*)d_in[14];
  const float* fcW  = (const float*)d_in[15];
  const float* fcb  = (const float*)d_in[16];
  const float* fcfW = (const float*)d_in[17];
  const float* fcfb = (const float*)d_in[18];
  float* out = (float*)d_out;

  const int B = in_sizes[0] / (T_ * 128);
  const size_t needQ = (size_t)B * QS * sizeof(u16);
  if (ws_size >= needQ && (B % BPB) == 0) {
    darnn4<<<dim3(B / BPB), dim3(NT), 0, stream>>>(
        X, eWih, eWhh, ebih, ebhh, eAw, eAb,
        dW1, db1, dW2, db2, dWih, dWhh, dbih, dbhh,
        fcW, fcb, fcfW, fcfb, (u16*)d_ws, out);
  } else {
    darnn_fb<<<dim3(B), dim3(NT), 0, stream>>>(
        X, eWih, eWhh, ebih, ebhh, eAw,
        dW1, db1, dW2, dWih, dWhh, dbih, dbhh,
        fcW, fcb, fcfW, fcfb, out);
  }
}

// Round 11
// 632.226 us; speedup vs baseline: 1.7866x; 1.0258x over previous
//
#include <hip/hip_runtime.h>

// DA-RNN fused — R19: S2 operands register-resident.
//  * R18 post-mortem: 734->648 (dispatch 599), MfmaUtil 10.6%, VALU 43%.
//    ~46% of issue slots are latency stalls at fixed 8 waves/CU (grid=256,
//    1 block/CU). Lever: shorten S2's in-wave critical path.
//  * Key: S2's E1 operand is STATIC over the decoder (each thread re-reads its
//    own (t=hh, q4-strip) slice every step), as are w2 and sye. Hoist into
//    registers (e1r 64 VGPR + w2r 16 + sye 2). Occupancy is LDS-bound -> VGPR
//    headroom to ~256 is free (launch_bounds(512,1)).
//  * S2 LDS traffic 72 -> 32 reads/step (su2 only, genuinely dynamic).
//  * Everything else identical to R18.

typedef unsigned int   u32;
typedef unsigned short u16;

#define T_  100
#define C_  32
#define NT  512
#define BPB 4
#define TS  132
#define QS  (T_ * NT)
#define SP  160   // shp/scp padded row (u16)

typedef __attribute__((ext_vector_type(2))) __fp16 h16x2;
typedef __attribute__((ext_vector_type(8))) __fp16 h16x8;
typedef __attribute__((ext_vector_type(4))) float  f32x4;

#if __has_builtin(__builtin_amdgcn_fdot2)
#define HAVE_FDOT2 1
#else
#define HAVE_FDOT2 0
#endif

__device__ __forceinline__ u32 pkh2(float a, float b) {
#if __has_builtin(__builtin_amdgcn_cvt_pkrtz)
  h16x2 p = __builtin_amdgcn_cvt_pkrtz(a, b);
  return __builtin_bit_cast(u32, p);
#else
  union { __fp16 h[2]; u32 u; } v;
  v.h[0] = (__fp16)a; v.h[1] = (__fp16)b;
  return v.u;
#endif
}
__device__ __forceinline__ void unph(u32 p, float& lo, float& hi) {
  union { u32 u; __fp16 h[2]; } v; v.u = p;
  lo = (float)v.h[0]; hi = (float)v.h[1];
}
__device__ __forceinline__ u16 f2h(float f) {
  union { __fp16 h; u16 u; } v; v.h = (__fp16)f; return v.u;
}
__device__ __forceinline__ float h2f(u16 u) {
  union { u16 u; __fp16 h; } v; v.u = u; return (float)v.h;
}
__device__ __forceinline__ float dot2h(u32 w, u32 x, float acc) {
#if HAVE_FDOT2
  return __builtin_amdgcn_fdot2(__builtin_bit_cast(h16x2, w),
                                __builtin_bit_cast(h16x2, x),
                                acc, false);
#else
  float a, b, c, d;
  unph(w, a, b); unph(x, c, d);
  return fmaf(a, c, fmaf(b, d, acc));
#endif
}
// pack 8 consecutive floats at p into 8 fp16 (A-fragment)
__device__ __forceinline__ h16x8 pack8(const float* p) {
  float4 v0 = *(const float4*)p;
  float4 v1 = *(const float4*)(p + 4);
  uint4 u;
  u.x = pkh2(v0.x, v0.y); u.y = pkh2(v0.z, v0.w);
  u.z = pkh2(v1.x, v1.y); u.w = pkh2(v1.z, v1.w);
  return __builtin_bit_cast(h16x8, u);
}
// load 8 consecutive fp16 (B-fragment) — LDS or global
__device__ __forceinline__ h16x8 ldb(const u16* p, int off) {
  return __builtin_bit_cast(h16x8, *(const uint4*)(p + off));
}

#if __has_builtin(__builtin_amdgcn_rcpf)
__device__ __forceinline__ float rcpf_(float x){ return __builtin_amdgcn_rcpf(x); }
#else
__device__ __forceinline__ float rcpf_(float x){ return 1.0f / x; }
#endif
__device__ __forceinline__ float sigm(float x){ return rcpf_(1.0f + __expf(-x)); }
__device__ __forceinline__ float tanh_(float x){
  return 1.0f - 2.0f * rcpf_(1.0f + __expf(2.0f * x));
}
// packed-fp16 tanh approx of (e+u), both packed half2 as u32
__device__ __forceinline__ u32 tanhpk(u32 eu, u32 uu) {
  h16x2 x = __builtin_bit_cast(h16x2, eu) + __builtin_bit_cast(h16x2, uu);
  const h16x2 one  = {(__fp16)1.0f,  (__fp16)1.0f};
#if __has_builtin(__builtin_elementwise_max) && __has_builtin(__builtin_elementwise_min)
  const h16x2 mone = {(__fp16)-1.0f, (__fp16)-1.0f};
  x = __builtin_elementwise_min(one, __builtin_elementwise_max(x, mone));
#else
  {
    float lo, hi; unph(__builtin_bit_cast(u32, x), lo, hi);
    x = (h16x2){(__fp16)fminf(1.f, fmaxf(-1.f, lo)),
                (__fp16)fminf(1.f, fmaxf(-1.f, hi))};
  }
#endif
  h16x2 x2 = x * x;
  const h16x2 c1 = {(__fp16)0.1333333f,  (__fp16)0.1333333f};
  const h16x2 c0 = {(__fp16)-0.3333333f, (__fp16)-0.3333333f};
  h16x2 r = x * (x2 * (x2 * c1 + c0) + one);
  return __builtin_bit_cast(u32, r);
}
__device__ __forceinline__ float ptanh(float x){
  x = fminf(1.0f, fmaxf(-1.0f, x));
  float x2 = x * x;
  float p  = fmaf(x2, 0.1333333f, -0.3333333f);
  return x * fmaf(x2, p, 1.0f);
}
__device__ __forceinline__ float wsum(float v){
  #pragma unroll
  for (int o = 32; o; o >>= 1) v += __shfl_xor(v, o, 64);
  return v;
}

// ============================ fast kernel (4 batches/block) =================
__global__ void __launch_bounds__(NT, 1)
darnn4(const float* __restrict__ X,
       const float* __restrict__ eWih, const float* __restrict__ eWhh,
       const float* __restrict__ ebih, const float* __restrict__ ebhh,
       const float* __restrict__ eAw,  const float* __restrict__ eAb,
       const float* __restrict__ dW1,  const float* __restrict__ db1,
       const float* __restrict__ dW2,  const float* __restrict__ db2,
       const float* __restrict__ dWih, const float* __restrict__ dWhh,
       const float* __restrict__ dbih, const float* __restrict__ dbhh,
       const float* __restrict__ fcW,  const float* __restrict__ fcb,
       const float* __restrict__ fcfW, const float* __restrict__ fcfb,
       u16* __restrict__ qws,
       float* __restrict__ out)
{
  // LDS ~131.1 KB
  __shared__ __align__(16) u16   sE1[BPB][T_ * TS];  // x_tilde -> E1   105600
  __shared__ __align__(16) float sg[BPB][520];       // gates (padded)   8320
  __shared__ __align__(16) float sh[BPB][128];       // h/d fp32         2048
  __shared__ __align__(16) float sc[BPB][128];       // c fp32           2048
  __shared__ __align__(16) u16   shp[BPB][SP];       // h/d fp16 (pad)   1280
  __shared__ __align__(16) u16   scp[BPB][SP];       // c fp16 (pad)     1280
  __shared__ __align__(16) float su[BPB][128];       // ctx              2048
  __shared__ __align__(16) float spart[BPB][512];    // partials         8192
  __shared__ __align__(16) float sye[BPB][128];      // ye -> beta       2048
  __shared__ __align__(16) u32   su2[BPB][68];       // packed u (pad)   1088
  __shared__ __align__(16) u32   sw2p[64];           // packed w2         256
  __shared__ float sred[16];

  const int tid  = threadIdx.x;
  const int lane = tid & 63;
  const int wv   = tid >> 6;     // 0..7
  const int hh   = tid & 127;
  const int q4   = tid >> 7;     // 0..3
  const int nn   = lane & 15;    // MFMA col
  const int kg   = lane >> 4;    // MFMA k-group
  const bool wr  = (nn < BPB);   // gate-MFMA result lanes
  const int tq   = nn >> 2;      // t offset within 16-col (t,bg) tile
  const int bq   = nn & 3;       // batch within tile
  const int b0   = blockIdx.x * BPB;

  (void)eAb; (void)db2;          // cancel under softmax shift-invariance

  if (tid < 64) sw2p[tid] = pkh2(dW2[2 * tid], dW2[2 * tid + 1]);

  // ---------- alpha (no max-sub; h/c terms cancel) + x_tilde ----------
  {
    const float* xp = X + (size_t)(b0 + q4) * 12800 + hh;
    float sval = 0.f;
    #pragma unroll 4
    for (int t = 0; t < T_; ++t) sval += xp[t * 128] * eAw[256 + t];
    float e = __expf(sval);
    float s = wsum(e);
    if (lane == 0) sred[wv] = s;
    __syncthreads();
    float al = e * rcpf_(sred[q4 * 2] + sred[q4 * 2 + 1]);
    #pragma unroll 4
    for (int t = 0; t < T_; ++t)
      sE1[q4][t * TS + hh] = f2h(al * xp[t * 128]);
    sh[q4][hh] = 0.f; sc[q4][hh] = 0.f; shp[q4][hh] = 0; scp[q4][hh] = 0;
  }
  __syncthreads();

  // ---------- Q GEMM via MFMA: Q[b][t][r] = eWih[r,:]·x_tilde ----------
  {
    h16x8 aQ[16];
    #pragma unroll
    for (int mt = 0; mt < 4; ++mt)
      #pragma unroll
      for (int ks = 0; ks < 4; ++ks)
        aQ[mt*4+ks] = pack8(eWih + (size_t)(wv*64 + mt*16 + nn) * 128
                            + ks*32 + kg*8);
    #pragma unroll 1
    for (int tn = 0; tn < 25; ++tn) {
      const int t = tn * 4 + tq;
      const u16* xb = &sE1[bq][t * TS];
      f32x4 c0={0,0,0,0}, c1={0,0,0,0}, c2={0,0,0,0}, c3={0,0,0,0};
      #pragma unroll
      for (int ks = 0; ks < 4; ++ks) {
        h16x8 b = ldb(xb, ks*32 + kg*8);
        c0 = __builtin_amdgcn_mfma_f32_16x16x32_f16(aQ[0*4+ks], b, c0, 0,0,0);
        c1 = __builtin_amdgcn_mfma_f32_16x16x32_f16(aQ[1*4+ks], b, c1, 0,0,0);
        c2 = __builtin_amdgcn_mfma_f32_16x16x32_f16(aQ[2*4+ks], b, c2, 0,0,0);
        c3 = __builtin_amdgcn_mfma_f32_16x16x32_f16(aQ[3*4+ks], b, c3, 0,0,0);
      }
      u16* qb = qws + (size_t)(b0 + bq) * QS + (size_t)t * NT + wv*64 + kg*4;
      uint2 p;
      p.x = pkh2(c0[0], c0[1]); p.y = pkh2(c0[2], c0[3]); *(uint2*)(qb)      = p;
      p.x = pkh2(c1[0], c1[1]); p.y = pkh2(c1[2], c1[3]); *(uint2*)(qb + 16) = p;
      p.x = pkh2(c2[0], c2[1]); p.y = pkh2(c2[2], c2[3]); *(uint2*)(qb + 32) = p;
      p.x = pkh2(c3[0], c3[1]); p.y = pkh2(c3[2], c3[3]); *(uint2*)(qb + 48) = p;
    }
  }
  __syncthreads();   // Q consumed cross-thread by encoder

  // ---------- encoder (MFMA gates; 2 barriers/step) ----------
  {
    h16x8 aH[16];
    #pragma unroll
    for (int rt = 0; rt < 4; ++rt)
      #pragma unroll
      for (int ks = 0; ks < 4; ++ks)
        aH[rt*4+ks] = pack8(eWhh + (size_t)(wv*64 + rt*16 + nn) * 128
                            + ks*32 + kg*8);
    float bgx = ebih[hh]       + ebhh[hh];
    float bgy = ebih[hh + 128] + ebhh[hh + 128];
    float bgz = ebih[hh + 256] + ebhh[hh + 256];
    float bgw = ebih[hh + 384] + ebhh[hh + 384];
    const u16* qrow = qws + (size_t)(b0 + q4) * QS + hh;

    for (int t = 0; t < T_; ++t) {
      u16 qv0 = qrow[t * NT];
      u16 qv1 = qrow[t * NT + 128];
      u16 qv2 = qrow[t * NT + 256];
      u16 qv3 = qrow[t * NT + 384];
      f32x4 g0 = {0,0,0,0}, g1 = {0,0,0,0}, g2 = {0,0,0,0}, g3 = {0,0,0,0};
      #pragma unroll
      for (int ks = 0; ks < 4; ++ks) {
        h16x8 b = ldb(&shp[nn & 3][0], ks*32 + kg*8);
        g0 = __builtin_amdgcn_mfma_f32_16x16x32_f16(aH[0*4+ks], b, g0, 0,0,0);
        g1 = __builtin_amdgcn_mfma_f32_16x16x32_f16(aH[1*4+ks], b, g1, 0,0,0);
        g2 = __builtin_amdgcn_mfma_f32_16x16x32_f16(aH[2*4+ks], b, g2, 0,0,0);
        g3 = __builtin_amdgcn_mfma_f32_16x16x32_f16(aH[3*4+ks], b, g3, 0,0,0);
      }
      if (wr) {
        *(f32x4*)(&sg[nn][wv*64 +  0 + kg*4]) = g0;
        *(f32x4*)(&sg[nn][wv*64 + 16 + kg*4]) = g1;
        *(f32x4*)(&sg[nn][wv*64 + 32 + kg*4]) = g2;
        *(f32x4*)(&sg[nn][wv*64 + 48 + kg*4]) = g3;
      }
      __syncthreads();
      {
        float gi = sigm (sg[q4][hh]       + bgx + h2f(qv0));
        float gf = sigm (sg[q4][hh + 128] + bgy + h2f(qv1));
        float gg = tanh_(sg[q4][hh + 256] + bgz + h2f(qv2));
        float go = sigm (sg[q4][hh + 384] + bgw + h2f(qv3));
        float c  = gf * sc[q4][hh] + gi * gg;
        sc[q4][hh] = c;
        float h  = go * tanh_(c);
        sh[q4][hh] = h;
        u16 hb = f2h(h);
        shp[q4][hh] = hb;
        scp[q4][hh] = f2h(c);
        // Xe row t shares Q's slab (Q[t] consumed pre-barrier; reg-held)
        qws[(size_t)(b0 + q4) * QS + t * NT + hh] = hb;
      }
      __syncthreads();
    }
  }

  // ---------- ye[t] = fcW · Xe[t]  ----------
  if (hh < T_) {
    #pragma unroll 1
    for (int bg = 0; bg < BPB; ++bg) {
      const uint2* xe = (const uint2*)(qws + (size_t)(b0 + bg) * QS
                                       + hh * NT + q4 * 32);
      const float* fw = fcW + q4 * 32;
      float a = 0.f;
      #pragma unroll
      for (int k = 0; k < 8; ++k) {
        uint2 xv = xe[k];
        float l0, l1, l2, l3;
        unph(xv.x, l0, l1); unph(xv.y, l2, l3);
        a += fw[4*k]*l0 + fw[4*k+1]*l1 + fw[4*k+2]*l2 + fw[4*k+3]*l3;
      }
      spart[bg][hh * 4 + q4] = a;
    }
  }
  __syncthreads();
  if (hh < T_) {
    float4 p = ((const float4*)spart[q4])[hh];
    sye[q4][hh] = (p.x + p.y) + (p.z + p.w);
  }
  __syncthreads();

  // ---------- E1 via MFMA: E1[t][h] = dW1[h][256:384]·Xe[t] + db1[h] ------
  {
    h16x8 aE[4];
    #pragma unroll
    for (int ks = 0; ks < 4; ++ks)
      aE[ks] = pack8(dW1 + (size_t)(wv*16 + nn) * 384 + 256 + ks*32 + kg*8);
    float4 b1 = *(const float4*)(db1 + wv*16 + kg*4);
    #pragma unroll 1
    for (int tn = 0; tn < 25; ++tn) {
      const int t = tn * 4 + tq;
      const u16* xb = qws + (size_t)(b0 + bq) * QS + (size_t)t * NT;
      f32x4 c = {0,0,0,0};
      #pragma unroll
      for (int ks = 0; ks < 4; ++ks) {
        h16x8 b = ldb(xb, ks*32 + kg*8);
        c = __builtin_amdgcn_mfma_f32_16x16x32_f16(aE[ks], b, c, 0,0,0);
      }
      uint2 p;
      p.x = pkh2(c[0] + b1.x, c[1] + b1.y);
      p.y = pkh2(c[2] + b1.z, c[3] + b1.w);
      *(uint2*)(&sE1[bq][t * TS + wv*16 + kg*4]) = p;
    }
  }

  // ---------- decoder weights (MFMA A-fragments) ----------
  h16x8 aD[16];   // dWhh rows [wv*64, +64)
  #pragma unroll
  for (int rt = 0; rt < 4; ++rt)
    #pragma unroll
    for (int ks = 0; ks < 4; ++ks)
      aD[rt*4+ks] = pack8(dWhh + (size_t)(wv*64 + rt*16 + nn) * 128
                          + ks*32 + kg*8);
  h16x8 aU[8];    // dW1 z-part rows [wv*16, +16), cols 0..255
  #pragma unroll
  for (int ks = 0; ks < 8; ++ks)
    aU[ks] = pack8(dW1 + (size_t)(wv*16 + nn) * 384 + ks*32 + kg*8);
  float bdx = dbih[hh]       + dbhh[hh];
  float bdy = dbih[hh + 128] + dbhh[hh + 128];
  float bdz = dbih[hh + 256] + dbhh[hh + 256];
  float bdw = dbih[hh + 384] + dbhh[hh + 384];
  float wix = dWih[hh];
  float wiy = dWih[hh + 128];
  float wiz = dWih[hh + 256];
  float wiw = dWih[hh + 384];
  float fcbv = fcb[0];
  sh[q4][hh] = 0.f; sc[q4][hh] = 0.f; shp[q4][hh] = 0; scp[q4][hh] = 0;
  __syncthreads();   // E1 writes + state init complete

  // ---------- S2 static operands -> registers (E1 strip, w2 strip, ye) ----
  uint2 e1r0[8], e1r1[8], e1r2[8], e1r3[8];  // E1[bg][hh*TS + q4*32 + ...]
  uint2 w2r[8];
  float ye0 = 0.f, ye1 = 0.f;
  if (hh < T_) {
    const uint2* s0 = (const uint2*)(&sE1[0][hh * TS + q4 * 32]);
    const uint2* s1 = (const uint2*)(&sE1[1][hh * TS + q4 * 32]);
    const uint2* s2 = (const uint2*)(&sE1[2][hh * TS + q4 * 32]);
    const uint2* s3 = (const uint2*)(&sE1[3][hh * TS + q4 * 32]);
    const uint2* wp = (const uint2*)(sw2p + q4 * 16);
    #pragma unroll
    for (int j = 0; j < 8; ++j) {
      e1r0[j] = s0[j];
      e1r1[j] = s1[j];
      e1r2[j] = s2[j];
      e1r3[j] = s3[j];
      w2r[j]  = wp[j];
    }
  }
  ye0 = sye[q4][lane];
  if (lane < 36) ye1 = sye[q4][64 + lane];

  // ---------- decoder (3 barriers/step) ----------
  for (int step = 0; step < T_; ++step) {
    // P1 (S0, MFMA): u = dW1z · [d;c]; wave wv owns u-rows [wv*16,+16)
    {
      f32x4 au = {0,0,0,0};
      #pragma unroll
      for (int ks = 0; ks < 8; ++ks) {
        const u16* bp = (ks < 4) ? &shp[nn & 3][0] : &scp[nn & 3][0];
        h16x8 b = ldb(bp, (ks & 3)*32 + kg*8);
        au = __builtin_amdgcn_mfma_f32_16x16x32_f16(aU[ks], b, au, 0,0,0);
      }
      if (wr) {
        uint2 up;
        up.x = pkh2(au[0], au[1]);
        up.y = pkh2(au[2], au[3]);
        *(uint2*)(&su2[nn][wv*8 + kg*2]) = up;
      }
    }
    __syncthreads();
    // P2 (S6 MFMA overlapped under S2 VALU)
    f32x4 g0 = {0,0,0,0}, g1 = {0,0,0,0}, g2 = {0,0,0,0}, g3 = {0,0,0,0};
    #pragma unroll
    for (int ks = 0; ks < 4; ++ks) {
      h16x8 b = ldb(&shp[nn & 3][0], ks*32 + kg*8);
      g0 = __builtin_amdgcn_mfma_f32_16x16x32_f16(aD[0*4+ks], b, g0, 0,0,0);
      g1 = __builtin_amdgcn_mfma_f32_16x16x32_f16(aD[1*4+ks], b, g1, 0,0,0);
      g2 = __builtin_amdgcn_mfma_f32_16x16x32_f16(aD[2*4+ks], b, g2, 0,0,0);
      g3 = __builtin_amdgcn_mfma_f32_16x16x32_f16(aD[3*4+ks], b, g3, 0,0,0);
    }
    // S2: score partials, packed fp16, reg-fed E1/w2; only su2 from LDS
    if (hh < T_) {
      const uint2* u0p = (const uint2*)(su2[0] + q4 * 16);
      const uint2* u1p = (const uint2*)(su2[1] + q4 * 16);
      const uint2* u2p = (const uint2*)(su2[2] + q4 * 16);
      const uint2* u3p = (const uint2*)(su2[3] + q4 * 16);
      float ac0 = 0.f, ac1 = 0.f, ac2 = 0.f, ac3 = 0.f;
      #pragma unroll
      for (int j = 0; j < 8; ++j) {
        uint2 w2v = w2r[j];
        uint2 uv;
        uv = u0p[j];
        ac0 = dot2h(w2v.x, tanhpk(e1r0[j].x, uv.x), ac0);
        ac0 = dot2h(w2v.y, tanhpk(e1r0[j].y, uv.y), ac0);
        uv = u1p[j];
        ac1 = dot2h(w2v.x, tanhpk(e1r1[j].x, uv.x), ac1);
        ac1 = dot2h(w2v.y, tanhpk(e1r1[j].y, uv.y), ac1);
        uv = u2p[j];
        ac2 = dot2h(w2v.x, tanhpk(e1r2[j].x, uv.x), ac2);
        ac2 = dot2h(w2v.y, tanhpk(e1r2[j].y, uv.y), ac2);
        uv = u3p[j];
        ac3 = dot2h(w2v.x, tanhpk(e1r3[j].x, uv.x), ac3);
        ac3 = dot2h(w2v.y, tanhpk(e1r3[j].y, uv.y), ac3);
      }
      spart[0][hh * 4 + q4] = ac0;
      spart[1][hh * 4 + q4] = ac1;
      spart[2][hh * 4 + q4] = ac2;
      spart[3][hh * 4 + q4] = ac3;
    }
    if (wr) {
      *(f32x4*)(&sg[nn][wv*64 +  0 + kg*4]) = g0;
      *(f32x4*)(&sg[nn][wv*64 + 16 + kg*4]) = g1;
      *(f32x4*)(&sg[nn][wv*64 + 32 + kg*4]) = g2;
      *(f32x4*)(&sg[nn][wv*64 + 48 + kg*4]) = g3;
    }
    __syncthreads();
    // P3 (S3+S7): softmax + y for own quad; pointwise LSTM with bias+y inject
    {
      float yv;
      {
        const int bg = q4;
        float4 p0 = ((const float4*)spart[bg])[lane];
        float e0 = __expf((p0.x + p0.y) + (p0.z + p0.w));
        float es = e0, ys = e0 * ye0;
        if (lane < 36) {
          float4 p1 = ((const float4*)spart[bg])[64 + lane];
          float e1 = __expf((p1.x + p1.y) + (p1.z + p1.w));
          es += e1; ys += e1 * ye1;
        }
        es = wsum(es); ys = wsum(ys);
        yv = ys * rcpf_(es) + fcbv;
      }
      float gi = sigm (sg[q4][hh]       + bdx + wix * yv);
      float gf = sigm (sg[q4][hh + 128] + bdy + wiy * yv);
      float gg = tanh_(sg[q4][hh + 256] + bdz + wiz * yv);
      float go = sigm (sg[q4][hh + 384] + bdw + wiw * yv);
      float c  = gf * sc[q4][hh] + gi * gg;
      sc[q4][hh] = c;
      float d  = go * tanh_(c);
      sh[q4][hh] = d;
      shp[q4][hh] = f2h(d);
      scp[q4][hh] = f2h(c);
    }
    __syncthreads();
  }

  // ---------- final beta -> ctx -> head ----------
  if (wv < BPB) {                     // wave w computes beta for batch w
    int bg = wv;
    float4 p0 = ((const float4*)spart[bg])[lane];
    float e0 = __expf((p0.x + p0.y) + (p0.z + p0.w));
    float e1 = 0.f;
    if (lane < 36) {
      float4 p1 = ((const float4*)spart[bg])[64 + lane];
      e1 = __expf((p1.x + p1.y) + (p1.z + p1.w));
    }
    float iv = rcpf_(wsum(e0 + e1));
    sye[bg][lane] = e0 * iv;          // overwrite ye with beta
    if (lane < 36) sye[bg][64 + lane] = e1 * iv;
  }
  __syncthreads();
  {
    const u16* xeb = qws + (size_t)(b0 + q4) * QS + hh;
    float cx = 0.f;
    #pragma unroll 4
    for (int t = 0; t < T_; ++t)
      cx += sye[q4][t] * h2f(xeb[t * NT]);
    su[q4][hh] = cx;                  // ctx
  }
  __syncthreads();
  if (tid < BPB * C_) {
    int bg = tid >> 5, cls = tid & 31;
    const float* w = fcfW + (size_t)cls * 256;
    float acc = fcfb[cls];
    #pragma unroll 8
    for (int k = 0; k < 128; ++k)
      acc += w[k] * sh[bg][k] + w[128 + k] * su[bg][k];
    out[(size_t)(b0 + bg) * C_ + cls] = acc;
  }
}

// ================== fallback (R7 structure, no workspace) ==================
__global__ void __launch_bounds__(NT)
darnn_fb(const float* __restrict__ X,
         const float* __restrict__ eWih, const float* __restrict__ eWhh,
         const float* __restrict__ ebih, const float* __restrict__ ebhh,
         const float* __restrict__ eAw,
         const float* __restrict__ dW1,  const float* __restrict__ db1,
         const float* __restrict__ dW2,
         const float* __restrict__ dWih, const float* __restrict__ dWhh,
         const float* __restrict__ dbih, const float* __restrict__ dbhh,
         const float* __restrict__ fcW,  const float* __restrict__ fcb,
         const float* __restrict__ fcfW, const float* __restrict__ fcfb,
         float* __restrict__ out)
{
  __shared__ __align__(16) u16   sxh[12800];
  __shared__ __align__(16) u16   sXe[12800];
  __shared__ __align__(16) float sg[512];
  __shared__ __align__(16) float sh[128];
  __shared__ __align__(16) float sc[128];
  __shared__ __align__(16) u16   shp[128];
  __shared__ __align__(16) u16   scp[128];
  __shared__ __align__(16) float su[128];
  __shared__ __align__(16) float spart[512];
  __shared__ __align__(16) float sscore[128];
  __shared__ __align__(16) float sctx[128];
  __shared__ float sred[8];
  __shared__ float sredY[2];

  const int tid  = threadIdx.x;
  const int lane = tid & 63;
  const int wv   = tid >> 6;
  const int b    = blockIdx.x;
  const int hh   = tid & 127;
  const int q4   = tid >> 7;

  {
    const float4* Xb4 = (const float4*)(X + (size_t)b * 12800);
    u32* dst = (u32*)sxh;
    #pragma unroll
    for (int i = 0; i < 7; ++i) {
      int idx = tid + NT * i;
      if (idx < 3200) {
        float4 v = Xb4[idx];
        dst[2*idx]   = pkh2(v.x, v.y);
        dst[2*idx+1] = pkh2(v.z, v.w);
      }
    }
  }
  __syncthreads();
  float sval = 0.f;
  if (tid < 128) {
    #pragma unroll 4
    for (int t = 0; t < T_; ++t)
      sval += h2f(sxh[t * 128 + tid]) * eAw[256 + t];
  }
  float ee = (tid < 128) ? __expf(sval) : 0.f;
  float sm = wsum(ee);
  if (lane == 0 && wv < 2) sred[2 + wv] = sm;
  __syncthreads();
  if (tid < 128) {
    su[tid] = ee * rcpf_(sred[2] + sred[3]);
    sh[tid] = 0.f; sc[tid] = 0.f; shp[tid] = 0; scp[tid] = 0;
  }
  __syncthreads();
  {
    u32* sx32 = (u32*)sxh;
    #pragma unroll
    for (int i = 0; i < 13; ++i) {
      int p = tid + NT * i;
      if (p < 6400) {
        float lo, hi; unph(sx32[p], lo, hi);
        int m = (2 * p) & 127;
        sx32[p] = pkh2(lo * su[m], hi * su[m + 1]);
      }
    }
  }
  __syncthreads();

  u32 wpkH[64], wpkI[64];
  {
    const float4* wr = (const float4*)(eWhh + (size_t)tid * 128);
    #pragma unroll
    for (int i = 0; i < 32; ++i) {
      float4 v = wr[i];
      wpkH[2*i] = pkh2(v.x, v.y); wpkH[2*i+1] = pkh2(v.z, v.w);
    }
    const float4* wi = (const float4*)(eWih + (size_t)tid * 128);
    #pragma unroll
    for (int i = 0; i < 32; ++i) {
      float4 v = wi[i];
      wpkI[2*i] = pkh2(v.x, v.y); wpkI[2*i+1] = pkh2(v.z, v.w);
    }
  }
  float biasg = ebih[tid] + ebhh[tid];

  for (int t = 0; t < T_; ++t) {
    float a0 = biasg, a1 = 0.f, a2 = 0.f, a3 = 0.f;
    const uint4* hr = (const uint4*)(const u32*)shp;
    #pragma unroll
    for (int k = 0; k < 16; ++k) {
      uint4 hv = hr[k];
      a0 = dot2h(wpkH[4*k+0], hv.x, a0);
      a1 = dot2h(wpkH[4*k+1], hv.y, a1);
      a2 = dot2h(wpkH[4*k+2], hv.z, a2);
      a3 = dot2h(wpkH[4*k+3], hv.w, a3);
    }
    const uint4* xr = (const uint4*)((const u32*)sxh + t * 64);
    #pragma unroll
    for (int k = 0; k < 16; ++k) {
      uint4 xv = xr[k];
      a0 = dot2h(wpkI[4*k+0], xv.x, a0);
      a1 = dot2h(wpkI[4*k+1], xv.y, a1);
      a2 = dot2h(wpkI[4*k+2], xv.z, a2);
      a3 = dot2h(wpkI[4*k+3], xv.w, a3);
    }
    sg[tid] = (a0 + a1) + (a2 + a3);
    __syncthreads();
    if (tid < 128) {
      float gi = sigm(sg[tid]);
      float gf = sigm(sg[tid + 128]);
      float gg = tanh_(sg[tid + 256]);
      float go = sigm(sg[tid + 384]);
      float c  = gf * sc[tid] + gi * gg;
      sc[tid]  = c;
      float h  = go * tanh_(c);
      sh[tid]  = h;
      u16 hb = f2h(h);
      shp[tid] = hb; scp[tid] = f2h(c);
      sXe[t * 128 + tid] = hb;
    }
    __syncthreads();
  }

  {
    u32 wtp[64];
    const float4* w4 = (const float4*)(dW1 + (size_t)hh * 384 + 256);
    #pragma unroll
    for (int i = 0; i < 32; ++i) {
      float4 v = w4[i];
      wtp[2*i] = pkh2(v.x, v.y); wtp[2*i+1] = pkh2(v.z, v.w);
    }
    float b1v = db1[hh];
    u16 e1out[25];
    #pragma unroll 1
    for (int i = 0; i < 25; ++i) {
      int t = q4 * 25 + i;
      const uint4* xe4 = (const uint4*)(sXe + t * 128);
      float a0 = 0.f, a1 = 0.f;
      #pragma unroll
      for (int k = 0; k < 16; ++k) {
        uint4 xv = xe4[k];
        a0 = dot2h(wtp[4*k+0], xv.x, a0);
        a1 = dot2h(wtp[4*k+1], xv.y, a1);
        a0 = dot2h(wtp[4*k+2], xv.z, a0);
        a1 = dot2h(wtp[4*k+3], xv.w, a1);
      }
      e1out[i] = f2h(a0 + a1 + b1v);
    }
    __syncthreads();
    #pragma unroll 1
    for (int i = 0; i < 25; ++i)
      sxh[(q4 * 25 + i) * 128 + hh] = e1out[i];
  }

  u32 wpkD[64];
  {
    const float4* wr = (const float4*)(dWhh + (size_t)tid * 128);
    #pragma unroll
    for (int i = 0; i < 32; ++i) {
      float4 v = wr[i];
      wpkD[2*i] = pkh2(v.x, v.y); wpkD[2*i+1] = pkh2(v.z, v.w);
    }
  }
  u32 wtpU[32];
  {
    const float4* wu = (const float4*)(dW1 + (size_t)hh * 384 + q4 * 64);
    #pragma unroll
    for (int i = 0; i < 16; ++i) {
      float4 v = wu[i];
      wtpU[2*i] = pkh2(v.x, v.y); wtpU[2*i+1] = pkh2(v.z, v.w);
    }
  }
  float biasD = dbih[tid] + dbhh[tid];
  float wihj  = dWih[tid];
  float w2a   = dW2[lane];
  float w2b   = dW2[lane + 64];
  float fcbv  = fcb[0];
  float fcwv  = (tid < 128) ? fcW[tid] : 0.f;
  if (tid < 128) { sh[tid] = 0.f; sc[tid] = 0.f; shp[tid] = 0; scp[tid] = 0; }
  __syncthreads();

  for (int step = 0; step < T_; ++step) {
    {
      const u32* base = (q4 < 2) ? (const u32*)shp : (const u32*)scp;
      const uint4* vp = (const uint4*)(base + (q4 & 1) * 32);
      float a0 = 0.f, a1 = 0.f;
      #pragma unroll
      for (int k = 0; k < 8; ++k) {
        uint4 v = vp[k];
        a0 = dot2h(wtpU[4*k+0], v.x, a0);
        a1 = dot2h(wtpU[4*k+1], v.y, a1);
        a0 = dot2h(wtpU[4*k+2], v.z, a0);
        a1 = dot2h(wtpU[4*k+3], v.w, a1);
      }
      spart[q4 * 128 + hh] = a0 + a1;
    }
    __syncthreads();
    {
      float ul = spart[lane] + spart[128 + lane]
               + spart[256 + lane] + spart[384 + lane];
      float uh = spart[64 + lane] + spart[192 + lane]
               + spart[320 + lane] + spart[448 + lane];
      #pragma unroll 1
      for (int i = 0; i < 13; ++i) {
        int t = wv + 8 * i;
        if (t < T_) {
          float v = w2a * ptanh(h2f(sxh[t * 128 + lane]) + ul)
                  + w2b * ptanh(h2f(sxh[t * 128 + 64 + lane]) + uh);
          v = wsum(v);
          if (lane == 0) sscore[t] = v;
        }
      }
    }
    __syncthreads();
    if (wv == 0) {
      float s0 = sscore[lane];
      float E0 = __expf(s0);
      float E1v = (lane < 36) ? __expf(sscore[lane + 64]) : 0.f;
      float s  = wsum(E0 + E1v);
      float iv = rcpf_(s);
      sscore[lane] = E0 * iv;
      if (lane < 36) sscore[lane + 64] = E1v * iv;
    }
    __syncthreads();
    {
      float pc = 0.f;
      #pragma unroll
      for (int i = 0; i < 25; ++i) {
        int t = q4 * 25 + i;
        pc += sscore[t] * h2f(sXe[t * 128 + hh]);
      }
      spart[q4 * 128 + hh] = pc;
    }
    __syncthreads();
    {
      float v = 0.f;
      if (tid < 128) {
        float cx = spart[tid] + spart[tid + 128]
                 + spart[tid + 256] + spart[tid + 384];
        sctx[tid] = cx;
        v = fcwv * cx;
      }
      v = wsum(v);
      if (lane == 0 && wv < 2) sredY[wv] = v;
    }
    __syncthreads();
    {
      float yt = sredY[0] + sredY[1] + fcbv;
      float a0 = biasD + wihj * yt, a1 = 0.f, a2 = 0.f, a3 = 0.f;
      const uint4* hr = (const uint4*)(const u32*)shp;
      #pragma unroll
      for (int k = 0; k < 16; ++k) {
        uint4 hv = hr[k];
        a0 = dot2h(wpkD[4*k+0], hv.x, a0);
        a1 = dot2h(wpkD[4*k+1], hv.y, a1);
        a2 = dot2h(wpkD[4*k+2], hv.z, a2);
        a3 = dot2h(wpkD[4*k+3], hv.w, a3);
      }
      sg[tid] = (a0 + a1) + (a2 + a3);
    }
    __syncthreads();
    if (tid < 128) {
      float gi = sigm(sg[tid]);
      float gf = sigm(sg[tid + 128]);
      float gg = tanh_(sg[tid + 256]);
      float go = sigm(sg[tid + 384]);
      float c  = gf * sc[tid] + gi * gg;
      sc[tid]  = c;
      float d  = go * tanh_(c);
      sh[tid]  = d;
      shp[tid] = f2h(d);
      scp[tid] = f2h(c);
    }
    __syncthreads();
  }

  if (tid < C_) {
    float acc = fcfb[tid];
    const float* w = fcfW + (size_t)tid * 256;
    #pragma unroll 8
    for (int k = 0; k < 128; ++k)
      acc += w[k] * sh[k] + w[128 + k] * sctx[k];
    out[(size_t)b * C_ + tid] = acc;
  }
}

extern "C" void kernel_launch(void* const* d_in, const int* in_sizes, int n_in,
                              void* d_out, int out_size, void* d_ws, size_t ws_size,
                              hipStream_t stream) {
  (void)n_in; (void)out_size;
  const float* X    = (const float*)d_in[0];
  const float* eWih = (const float*)d_in[1];
  const float* eWhh = (const float*)d_in[2];
  const float* ebih = (const float*)d_in[3];
  const float* ebhh = (const float*)d_in[4];
  const float* eAw  = (const float*)d_in[5];
  const float* eAb  = (const float*)d_in[6];
  const float* dW1  = (const float*)d_in[7];
  const float* db1  = (const float*)d_in[8];
  const float* dW2  = (const float*)d_in[9];
  const float* db2  = (const float*)d_in[10];
  const float* dWih = (const float*)d_in[11];
  const float* dWhh = (const float*)d_in[12];
  const float* dbih = (const float*)d_in[13];
  const float* dbhh = (const float*)d_in[14];
  const float* fcW  = (const float*)d_in[15];
  const float* fcb  = (const float*)d_in[16];
  const float* fcfW = (const float*)d_in[17];
  const float* fcfb = (const float*)d_in[18];
  float* out = (float*)d_out;

  const int B = in_sizes[0] / (T_ * 128);
  const size_t needQ = (size_t)B * QS * sizeof(u16);
  if (ws_size >= needQ && (B % BPB) == 0) {
    darnn4<<<dim3(B / BPB), dim3(NT), 0, stream>>>(
        X, eWih, eWhh, ebih, ebhh, eAw, eAb,
        dW1, db1, dW2, db2, dWih, dWhh, dbih, dbhh,
        fcW, fcb, fcfW, fcfb, (u16*)d_ws, out);
  } else {
    darnn_fb<<<dim3(B), dim3(NT), 0, stream>>>(
        X, eWih, eWhh, ebih, ebhh, eAw,
        dW1, db1, dW2, dWih, dWhh, dbih, dbhh,
        fcW, fcb, fcfW, fcfb, out);
  }
}

// Round 12
// 629.230 us; speedup vs baseline: 1.7951x; 1.0048x over previous
//
#include <hip/hip_runtime.h>

// DA-RNN fused — R20: unlock the 256-VGPR budget (amdgpu_waves_per_eu).
//  * R19 post-mortem: e1r/w2r hoist capped by the allocator's 128-VGPR
//    default -> persistent set (aD64+aU32+e1r64+w2r16 ~176) spilled once
//    (FETCH +27MB, WRITE +29MB, VGPR=128 exactly). At 1 block/CU (LDS-bound)
//    the HW budget is 2 waves/SIMD x 256 VGPR — unused.
//  * R20: __attribute__((amdgpu_waves_per_eu(2,2))) pins the allocator at
//    the true occupancy (2 waves/EU) -> 256 VGPR cap. No algorithmic change;
//    math bit-identical to R19.
//  * Confirmation signal: FETCH ~115MB / WRITE ~128MB (spill gone),
//    VGPR ~180-256.

typedef unsigned int   u32;
typedef unsigned short u16;

#define T_  100
#define C_  32
#define NT  512
#define BPB 4
#define TS  132
#define QS  (T_ * NT)
#define SP  160   // shp/scp padded row (u16)

typedef __attribute__((ext_vector_type(2))) __fp16 h16x2;
typedef __attribute__((ext_vector_type(8))) __fp16 h16x8;
typedef __attribute__((ext_vector_type(4))) float  f32x4;

#if __has_builtin(__builtin_amdgcn_fdot2)
#define HAVE_FDOT2 1
#else
#define HAVE_FDOT2 0
#endif

__device__ __forceinline__ u32 pkh2(float a, float b) {
#if __has_builtin(__builtin_amdgcn_cvt_pkrtz)
  h16x2 p = __builtin_amdgcn_cvt_pkrtz(a, b);
  return __builtin_bit_cast(u32, p);
#else
  union { __fp16 h[2]; u32 u; } v;
  v.h[0] = (__fp16)a; v.h[1] = (__fp16)b;
  return v.u;
#endif
}
__device__ __forceinline__ void unph(u32 p, float& lo, float& hi) {
  union { u32 u; __fp16 h[2]; } v; v.u = p;
  lo = (float)v.h[0]; hi = (float)v.h[1];
}
__device__ __forceinline__ u16 f2h(float f) {
  union { __fp16 h; u16 u; } v; v.h = (__fp16)f; return v.u;
}
__device__ __forceinline__ float h2f(u16 u) {
  union { u16 u; __fp16 h; } v; v.u = u; return (float)v.h;
}
__device__ __forceinline__ float dot2h(u32 w, u32 x, float acc) {
#if HAVE_FDOT2
  return __builtin_amdgcn_fdot2(__builtin_bit_cast(h16x2, w),
                                __builtin_bit_cast(h16x2, x),
                                acc, false);
#else
  float a, b, c, d;
  unph(w, a, b); unph(x, c, d);
  return fmaf(a, c, fmaf(b, d, acc));
#endif
}
// pack 8 consecutive floats at p into 8 fp16 (A-fragment)
__device__ __forceinline__ h16x8 pack8(const float* p) {
  float4 v0 = *(const float4*)p;
  float4 v1 = *(const float4*)(p + 4);
  uint4 u;
  u.x = pkh2(v0.x, v0.y); u.y = pkh2(v0.z, v0.w);
  u.z = pkh2(v1.x, v1.y); u.w = pkh2(v1.z, v1.w);
  return __builtin_bit_cast(h16x8, u);
}
// load 8 consecutive fp16 (B-fragment) — LDS or global
__device__ __forceinline__ h16x8 ldb(const u16* p, int off) {
  return __builtin_bit_cast(h16x8, *(const uint4*)(p + off));
}

#if __has_builtin(__builtin_amdgcn_rcpf)
__device__ __forceinline__ float rcpf_(float x){ return __builtin_amdgcn_rcpf(x); }
#else
__device__ __forceinline__ float rcpf_(float x){ return 1.0f / x; }
#endif
__device__ __forceinline__ float sigm(float x){ return rcpf_(1.0f + __expf(-x)); }
__device__ __forceinline__ float tanh_(float x){
  return 1.0f - 2.0f * rcpf_(1.0f + __expf(2.0f * x));
}
// packed-fp16 tanh approx of (e+u), both packed half2 as u32
__device__ __forceinline__ u32 tanhpk(u32 eu, u32 uu) {
  h16x2 x = __builtin_bit_cast(h16x2, eu) + __builtin_bit_cast(h16x2, uu);
  const h16x2 one  = {(__fp16)1.0f,  (__fp16)1.0f};
#if __has_builtin(__builtin_elementwise_max) && __has_builtin(__builtin_elementwise_min)
  const h16x2 mone = {(__fp16)-1.0f, (__fp16)-1.0f};
  x = __builtin_elementwise_min(one, __builtin_elementwise_max(x, mone));
#else
  {
    float lo, hi; unph(__builtin_bit_cast(u32, x), lo, hi);
    x = (h16x2){(__fp16)fminf(1.f, fmaxf(-1.f, lo)),
                (__fp16)fminf(1.f, fmaxf(-1.f, hi))};
  }
#endif
  h16x2 x2 = x * x;
  const h16x2 c1 = {(__fp16)0.1333333f,  (__fp16)0.1333333f};
  const h16x2 c0 = {(__fp16)-0.3333333f, (__fp16)-0.3333333f};
  h16x2 r = x * (x2 * (x2 * c1 + c0) + one);
  return __builtin_bit_cast(u32, r);
}
__device__ __forceinline__ float ptanh(float x){
  x = fminf(1.0f, fmaxf(-1.0f, x));
  float x2 = x * x;
  float p  = fmaf(x2, 0.1333333f, -0.3333333f);
  return x * fmaf(x2, p, 1.0f);
}
__device__ __forceinline__ float wsum(float v){
  #pragma unroll
  for (int o = 32; o; o >>= 1) v += __shfl_xor(v, o, 64);
  return v;
}

// ============================ fast kernel (4 batches/block) =================
__global__ void __launch_bounds__(NT, 1)
__attribute__((amdgpu_waves_per_eu(2, 2)))
darnn4(const float* __restrict__ X,
       const float* __restrict__ eWih, const float* __restrict__ eWhh,
       const float* __restrict__ ebih, const float* __restrict__ ebhh,
       const float* __restrict__ eAw,  const float* __restrict__ eAb,
       const float* __restrict__ dW1,  const float* __restrict__ db1,
       const float* __restrict__ dW2,  const float* __restrict__ db2,
       const float* __restrict__ dWih, const float* __restrict__ dWhh,
       const float* __restrict__ dbih, const float* __restrict__ dbhh,
       const float* __restrict__ fcW,  const float* __restrict__ fcb,
       const float* __restrict__ fcfW, const float* __restrict__ fcfb,
       u16* __restrict__ qws,
       float* __restrict__ out)
{
  // LDS ~131.1 KB
  __shared__ __align__(16) u16   sE1[BPB][T_ * TS];  // x_tilde -> E1   105600
  __shared__ __align__(16) float sg[BPB][520];       // gates (padded)   8320
  __shared__ __align__(16) float sh[BPB][128];       // h/d fp32         2048
  __shared__ __align__(16) float sc[BPB][128];       // c fp32           2048
  __shared__ __align__(16) u16   shp[BPB][SP];       // h/d fp16 (pad)   1280
  __shared__ __align__(16) u16   scp[BPB][SP];       // c fp16 (pad)     1280
  __shared__ __align__(16) float su[BPB][128];       // ctx              2048
  __shared__ __align__(16) float spart[BPB][512];    // partials         8192
  __shared__ __align__(16) float sye[BPB][128];      // ye -> beta       2048
  __shared__ __align__(16) u32   su2[BPB][68];       // packed u (pad)   1088
  __shared__ __align__(16) u32   sw2p[64];           // packed w2         256
  __shared__ float sred[16];

  const int tid  = threadIdx.x;
  const int lane = tid & 63;
  const int wv   = tid >> 6;     // 0..7
  const int hh   = tid & 127;
  const int q4   = tid >> 7;     // 0..3
  const int nn   = lane & 15;    // MFMA col
  const int kg   = lane >> 4;    // MFMA k-group
  const bool wr  = (nn < BPB);   // gate-MFMA result lanes
  const int tq   = nn >> 2;      // t offset within 16-col (t,bg) tile
  const int bq   = nn & 3;       // batch within tile
  const int b0   = blockIdx.x * BPB;

  (void)eAb; (void)db2;          // cancel under softmax shift-invariance

  if (tid < 64) sw2p[tid] = pkh2(dW2[2 * tid], dW2[2 * tid + 1]);

  // ---------- alpha (no max-sub; h/c terms cancel) + x_tilde ----------
  {
    const float* xp = X + (size_t)(b0 + q4) * 12800 + hh;
    float sval = 0.f;
    #pragma unroll 4
    for (int t = 0; t < T_; ++t) sval += xp[t * 128] * eAw[256 + t];
    float e = __expf(sval);
    float s = wsum(e);
    if (lane == 0) sred[wv] = s;
    __syncthreads();
    float al = e * rcpf_(sred[q4 * 2] + sred[q4 * 2 + 1]);
    #pragma unroll 4
    for (int t = 0; t < T_; ++t)
      sE1[q4][t * TS + hh] = f2h(al * xp[t * 128]);
    sh[q4][hh] = 0.f; sc[q4][hh] = 0.f; shp[q4][hh] = 0; scp[q4][hh] = 0;
  }
  __syncthreads();

  // ---------- Q GEMM via MFMA: Q[b][t][r] = eWih[r,:]·x_tilde ----------
  {
    h16x8 aQ[16];
    #pragma unroll
    for (int mt = 0; mt < 4; ++mt)
      #pragma unroll
      for (int ks = 0; ks < 4; ++ks)
        aQ[mt*4+ks] = pack8(eWih + (size_t)(wv*64 + mt*16 + nn) * 128
                            + ks*32 + kg*8);
    #pragma unroll 1
    for (int tn = 0; tn < 25; ++tn) {
      const int t = tn * 4 + tq;
      const u16* xb = &sE1[bq][t * TS];
      f32x4 c0={0,0,0,0}, c1={0,0,0,0}, c2={0,0,0,0}, c3={0,0,0,0};
      #pragma unroll
      for (int ks = 0; ks < 4; ++ks) {
        h16x8 b = ldb(xb, ks*32 + kg*8);
        c0 = __builtin_amdgcn_mfma_f32_16x16x32_f16(aQ[0*4+ks], b, c0, 0,0,0);
        c1 = __builtin_amdgcn_mfma_f32_16x16x32_f16(aQ[1*4+ks], b, c1, 0,0,0);
        c2 = __builtin_amdgcn_mfma_f32_16x16x32_f16(aQ[2*4+ks], b, c2, 0,0,0);
        c3 = __builtin_amdgcn_mfma_f32_16x16x32_f16(aQ[3*4+ks], b, c3, 0,0,0);
      }
      u16* qb = qws + (size_t)(b0 + bq) * QS + (size_t)t * NT + wv*64 + kg*4;
      uint2 p;
      p.x = pkh2(c0[0], c0[1]); p.y = pkh2(c0[2], c0[3]); *(uint2*)(qb)      = p;
      p.x = pkh2(c1[0], c1[1]); p.y = pkh2(c1[2], c1[3]); *(uint2*)(qb + 16) = p;
      p.x = pkh2(c2[0], c2[1]); p.y = pkh2(c2[2], c2[3]); *(uint2*)(qb + 32) = p;
      p.x = pkh2(c3[0], c3[1]); p.y = pkh2(c3[2], c3[3]); *(uint2*)(qb + 48) = p;
    }
  }
  __syncthreads();   // Q consumed cross-thread by encoder

  // ---------- encoder (MFMA gates; 2 barriers/step) ----------
  {
    h16x8 aH[16];
    #pragma unroll
    for (int rt = 0; rt < 4; ++rt)
      #pragma unroll
      for (int ks = 0; ks < 4; ++ks)
        aH[rt*4+ks] = pack8(eWhh + (size_t)(wv*64 + rt*16 + nn) * 128
                            + ks*32 + kg*8);
    float bgx = ebih[hh]       + ebhh[hh];
    float bgy = ebih[hh + 128] + ebhh[hh + 128];
    float bgz = ebih[hh + 256] + ebhh[hh + 256];
    float bgw = ebih[hh + 384] + ebhh[hh + 384];
    const u16* qrow = qws + (size_t)(b0 + q4) * QS + hh;

    for (int t = 0; t < T_; ++t) {
      u16 qv0 = qrow[t * NT];
      u16 qv1 = qrow[t * NT + 128];
      u16 qv2 = qrow[t * NT + 256];
      u16 qv3 = qrow[t * NT + 384];
      f32x4 g0 = {0,0,0,0}, g1 = {0,0,0,0}, g2 = {0,0,0,0}, g3 = {0,0,0,0};
      #pragma unroll
      for (int ks = 0; ks < 4; ++ks) {
        h16x8 b = ldb(&shp[nn & 3][0], ks*32 + kg*8);
        g0 = __builtin_amdgcn_mfma_f32_16x16x32_f16(aH[0*4+ks], b, g0, 0,0,0);
        g1 = __builtin_amdgcn_mfma_f32_16x16x32_f16(aH[1*4+ks], b, g1, 0,0,0);
        g2 = __builtin_amdgcn_mfma_f32_16x16x32_f16(aH[2*4+ks], b, g2, 0,0,0);
        g3 = __builtin_amdgcn_mfma_f32_16x16x32_f16(aH[3*4+ks], b, g3, 0,0,0);
      }
      if (wr) {
        *(f32x4*)(&sg[nn][wv*64 +  0 + kg*4]) = g0;
        *(f32x4*)(&sg[nn][wv*64 + 16 + kg*4]) = g1;
        *(f32x4*)(&sg[nn][wv*64 + 32 + kg*4]) = g2;
        *(f32x4*)(&sg[nn][wv*64 + 48 + kg*4]) = g3;
      }
      __syncthreads();
      {
        float gi = sigm (sg[q4][hh]       + bgx + h2f(qv0));
        float gf = sigm (sg[q4][hh + 128] + bgy + h2f(qv1));
        float gg = tanh_(sg[q4][hh + 256] + bgz + h2f(qv2));
        float go = sigm (sg[q4][hh + 384] + bgw + h2f(qv3));
        float c  = gf * sc[q4][hh] + gi * gg;
        sc[q4][hh] = c;
        float h  = go * tanh_(c);
        sh[q4][hh] = h;
        u16 hb = f2h(h);
        shp[q4][hh] = hb;
        scp[q4][hh] = f2h(c);
        // Xe row t shares Q's slab (Q[t] consumed pre-barrier; reg-held)
        qws[(size_t)(b0 + q4) * QS + t * NT + hh] = hb;
      }
      __syncthreads();
    }
  }

  // ---------- ye[t] = fcW · Xe[t]  ----------
  if (hh < T_) {
    #pragma unroll 1
    for (int bg = 0; bg < BPB; ++bg) {
      const uint2* xe = (const uint2*)(qws + (size_t)(b0 + bg) * QS
                                       + hh * NT + q4 * 32);
      const float* fw = fcW + q4 * 32;
      float a = 0.f;
      #pragma unroll
      for (int k = 0; k < 8; ++k) {
        uint2 xv = xe[k];
        float l0, l1, l2, l3;
        unph(xv.x, l0, l1); unph(xv.y, l2, l3);
        a += fw[4*k]*l0 + fw[4*k+1]*l1 + fw[4*k+2]*l2 + fw[4*k+3]*l3;
      }
      spart[bg][hh * 4 + q4] = a;
    }
  }
  __syncthreads();
  if (hh < T_) {
    float4 p = ((const float4*)spart[q4])[hh];
    sye[q4][hh] = (p.x + p.y) + (p.z + p.w);
  }
  __syncthreads();

  // ---------- E1 via MFMA: E1[t][h] = dW1[h][256:384]·Xe[t] + db1[h] ------
  {
    h16x8 aE[4];
    #pragma unroll
    for (int ks = 0; ks < 4; ++ks)
      aE[ks] = pack8(dW1 + (size_t)(wv*16 + nn) * 384 + 256 + ks*32 + kg*8);
    float4 b1 = *(const float4*)(db1 + wv*16 + kg*4);
    #pragma unroll 1
    for (int tn = 0; tn < 25; ++tn) {
      const int t = tn * 4 + tq;
      const u16* xb = qws + (size_t)(b0 + bq) * QS + (size_t)t * NT;
      f32x4 c = {0,0,0,0};
      #pragma unroll
      for (int ks = 0; ks < 4; ++ks) {
        h16x8 b = ldb(xb, ks*32 + kg*8);
        c = __builtin_amdgcn_mfma_f32_16x16x32_f16(aE[ks], b, c, 0,0,0);
      }
      uint2 p;
      p.x = pkh2(c[0] + b1.x, c[1] + b1.y);
      p.y = pkh2(c[2] + b1.z, c[3] + b1.w);
      *(uint2*)(&sE1[bq][t * TS + wv*16 + kg*4]) = p;
    }
  }

  // ---------- decoder weights (MFMA A-fragments) ----------
  h16x8 aD[16];   // dWhh rows [wv*64, +64)
  #pragma unroll
  for (int rt = 0; rt < 4; ++rt)
    #pragma unroll
    for (int ks = 0; ks < 4; ++ks)
      aD[rt*4+ks] = pack8(dWhh + (size_t)(wv*64 + rt*16 + nn) * 128
                          + ks*32 + kg*8);
  h16x8 aU[8];    // dW1 z-part rows [wv*16, +16), cols 0..255
  #pragma unroll
  for (int ks = 0; ks < 8; ++ks)
    aU[ks] = pack8(dW1 + (size_t)(wv*16 + nn) * 384 + ks*32 + kg*8);
  float bdx = dbih[hh]       + dbhh[hh];
  float bdy = dbih[hh + 128] + dbhh[hh + 128];
  float bdz = dbih[hh + 256] + dbhh[hh + 256];
  float bdw = dbih[hh + 384] + dbhh[hh + 384];
  float wix = dWih[hh];
  float wiy = dWih[hh + 128];
  float wiz = dWih[hh + 256];
  float wiw = dWih[hh + 384];
  float fcbv = fcb[0];
  sh[q4][hh] = 0.f; sc[q4][hh] = 0.f; shp[q4][hh] = 0; scp[q4][hh] = 0;
  __syncthreads();   // E1 writes + state init complete

  // ---------- S2 static operands -> registers (E1 strip, w2 strip, ye) ----
  uint2 e1r0[8], e1r1[8], e1r2[8], e1r3[8];  // E1[bg][hh*TS + q4*32 + ...]
  uint2 w2r[8];
  float ye0 = 0.f, ye1 = 0.f;
  if (hh < T_) {
    const uint2* s0 = (const uint2*)(&sE1[0][hh * TS + q4 * 32]);
    const uint2* s1 = (const uint2*)(&sE1[1][hh * TS + q4 * 32]);
    const uint2* s2 = (const uint2*)(&sE1[2][hh * TS + q4 * 32]);
    const uint2* s3 = (const uint2*)(&sE1[3][hh * TS + q4 * 32]);
    const uint2* wp = (const uint2*)(sw2p + q4 * 16);
    #pragma unroll
    for (int j = 0; j < 8; ++j) {
      e1r0[j] = s0[j];
      e1r1[j] = s1[j];
      e1r2[j] = s2[j];
      e1r3[j] = s3[j];
      w2r[j]  = wp[j];
    }
  }
  ye0 = sye[q4][lane];
  if (lane < 36) ye1 = sye[q4][64 + lane];

  // ---------- decoder (3 barriers/step) ----------
  for (int step = 0; step < T_; ++step) {
    // P1 (S0, MFMA): u = dW1z · [d;c]; wave wv owns u-rows [wv*16,+16)
    {
      f32x4 au = {0,0,0,0};
      #pragma unroll
      for (int ks = 0; ks < 8; ++ks) {
        const u16* bp = (ks < 4) ? &shp[nn & 3][0] : &scp[nn & 3][0];
        h16x8 b = ldb(bp, (ks & 3)*32 + kg*8);
        au = __builtin_amdgcn_mfma_f32_16x16x32_f16(aU[ks], b, au, 0,0,0);
      }
      if (wr) {
        uint2 up;
        up.x = pkh2(au[0], au[1]);
        up.y = pkh2(au[2], au[3]);
        *(uint2*)(&su2[nn][wv*8 + kg*2]) = up;
      }
    }
    __syncthreads();
    // P2 (S6 MFMA overlapped under S2 VALU)
    f32x4 g0 = {0,0,0,0}, g1 = {0,0,0,0}, g2 = {0,0,0,0}, g3 = {0,0,0,0};
    #pragma unroll
    for (int ks = 0; ks < 4; ++ks) {
      h16x8 b = ldb(&shp[nn & 3][0], ks*32 + kg*8);
      g0 = __builtin_amdgcn_mfma_f32_16x16x32_f16(aD[0*4+ks], b, g0, 0,0,0);
      g1 = __builtin_amdgcn_mfma_f32_16x16x32_f16(aD[1*4+ks], b, g1, 0,0,0);
      g2 = __builtin_amdgcn_mfma_f32_16x16x32_f16(aD[2*4+ks], b, g2, 0,0,0);
      g3 = __builtin_amdgcn_mfma_f32_16x16x32_f16(aD[3*4+ks], b, g3, 0,0,0);
    }
    // S2: score partials, packed fp16, reg-fed E1/w2; only su2 from LDS
    if (hh < T_) {
      const uint2* u0p = (const uint2*)(su2[0] + q4 * 16);
      const uint2* u1p = (const uint2*)(su2[1] + q4 * 16);
      const uint2* u2p = (const uint2*)(su2[2] + q4 * 16);
      const uint2* u3p = (const uint2*)(su2[3] + q4 * 16);
      float ac0 = 0.f, ac1 = 0.f, ac2 = 0.f, ac3 = 0.f;
      #pragma unroll
      for (int j = 0; j < 8; ++j) {
        uint2 w2v = w2r[j];
        uint2 uv;
        uv = u0p[j];
        ac0 = dot2h(w2v.x, tanhpk(e1r0[j].x, uv.x), ac0);
        ac0 = dot2h(w2v.y, tanhpk(e1r0[j].y, uv.y), ac0);
        uv = u1p[j];
        ac1 = dot2h(w2v.x, tanhpk(e1r1[j].x, uv.x), ac1);
        ac1 = dot2h(w2v.y, tanhpk(e1r1[j].y, uv.y), ac1);
        uv = u2p[j];
        ac2 = dot2h(w2v.x, tanhpk(e1r2[j].x, uv.x), ac2);
        ac2 = dot2h(w2v.y, tanhpk(e1r2[j].y, uv.y), ac2);
        uv = u3p[j];
        ac3 = dot2h(w2v.x, tanhpk(e1r3[j].x, uv.x), ac3);
        ac3 = dot2h(w2v.y, tanhpk(e1r3[j].y, uv.y), ac3);
      }
      spart[0][hh * 4 + q4] = ac0;
      spart[1][hh * 4 + q4] = ac1;
      spart[2][hh * 4 + q4] = ac2;
      spart[3][hh * 4 + q4] = ac3;
    }
    if (wr) {
      *(f32x4*)(&sg[nn][wv*64 +  0 + kg*4]) = g0;
      *(f32x4*)(&sg[nn][wv*64 + 16 + kg*4]) = g1;
      *(f32x4*)(&sg[nn][wv*64 + 32 + kg*4]) = g2;
      *(f32x4*)(&sg[nn][wv*64 + 48 + kg*4]) = g3;
    }
    __syncthreads();
    // P3 (S3+S7): softmax + y for own quad; pointwise LSTM with bias+y inject
    {
      float yv;
      {
        const int bg = q4;
        float4 p0 = ((const float4*)spart[bg])[lane];
        float e0 = __expf((p0.x + p0.y) + (p0.z + p0.w));
        float es = e0, ys = e0 * ye0;
        if (lane < 36) {
          float4 p1 = ((const float4*)spart[bg])[64 + lane];
          float e1 = __expf((p1.x + p1.y) + (p1.z + p1.w));
          es += e1; ys += e1 * ye1;
        }
        es = wsum(es); ys = wsum(ys);
        yv = ys * rcpf_(es) + fcbv;
      }
      float gi = sigm (sg[q4][hh]       + bdx + wix * yv);
      float gf = sigm (sg[q4][hh + 128] + bdy + wiy * yv);
      float gg = tanh_(sg[q4][hh + 256] + bdz + wiz * yv);
      float go = sigm (sg[q4][hh + 384] + bdw + wiw * yv);
      float c  = gf * sc[q4][hh] + gi * gg;
      sc[q4][hh] = c;
      float d  = go * tanh_(c);
      sh[q4][hh] = d;
      shp[q4][hh] = f2h(d);
      scp[q4][hh] = f2h(c);
    }
    __syncthreads();
  }

  // ---------- final beta -> ctx -> head ----------
  if (wv < BPB) {                     // wave w computes beta for batch w
    int bg = wv;
    float4 p0 = ((const float4*)spart[bg])[lane];
    float e0 = __expf((p0.x + p0.y) + (p0.z + p0.w));
    float e1 = 0.f;
    if (lane < 36) {
      float4 p1 = ((const float4*)spart[bg])[64 + lane];
      e1 = __expf((p1.x + p1.y) + (p1.z + p1.w));
    }
    float iv = rcpf_(wsum(e0 + e1));
    sye[bg][lane] = e0 * iv;          // overwrite ye with beta
    if (lane < 36) sye[bg][64 + lane] = e1 * iv;
  }
  __syncthreads();
  {
    const u16* xeb = qws + (size_t)(b0 + q4) * QS + hh;
    float cx = 0.f;
    #pragma unroll 4
    for (int t = 0; t < T_; ++t)
      cx += sye[q4][t] * h2f(xeb[t * NT]);
    su[q4][hh] = cx;                  // ctx
  }
  __syncthreads();
  if (tid < BPB * C_) {
    int bg = tid >> 5, cls = tid & 31;
    const float* w = fcfW + (size_t)cls * 256;
    float acc = fcfb[cls];
    #pragma unroll 8
    for (int k = 0; k < 128; ++k)
      acc += w[k] * sh[bg][k] + w[128 + k] * su[bg][k];
    out[(size_t)(b0 + bg) * C_ + cls] = acc;
  }
}

// ================== fallback (R7 structure, no workspace) ==================
__global__ void __launch_bounds__(NT)
darnn_fb(const float* __restrict__ X,
         const float* __restrict__ eWih, const float* __restrict__ eWhh,
         const float* __restrict__ ebih, const float* __restrict__ ebhh,
         const float* __restrict__ eAw,
         const float* __restrict__ dW1,  const float* __restrict__ db1,
         const float* __restrict__ dW2,
         const float* __restrict__ dWih, const float* __restrict__ dWhh,
         const float* __restrict__ dbih, const float* __restrict__ dbhh,
         const float* __restrict__ fcW,  const float* __restrict__ fcb,
         const float* __restrict__ fcfW, const float* __restrict__ fcfb,
         float* __restrict__ out)
{
  __shared__ __align__(16) u16   sxh[12800];
  __shared__ __align__(16) u16   sXe[12800];
  __shared__ __align__(16) float sg[512];
  __shared__ __align__(16) float sh[128];
  __shared__ __align__(16) float sc[128];
  __shared__ __align__(16) u16   shp[128];
  __shared__ __align__(16) u16   scp[128];
  __shared__ __align__(16) float su[128];
  __shared__ __align__(16) float spart[512];
  __shared__ __align__(16) float sscore[128];
  __shared__ __align__(16) float sctx[128];
  __shared__ float sred[8];
  __shared__ float sredY[2];

  const int tid  = threadIdx.x;
  const int lane = tid & 63;
  const int wv   = tid >> 6;
  const int b    = blockIdx.x;
  const int hh   = tid & 127;
  const int q4   = tid >> 7;

  {
    const float4* Xb4 = (const float4*)(X + (size_t)b * 12800);
    u32* dst = (u32*)sxh;
    #pragma unroll
    for (int i = 0; i < 7; ++i) {
      int idx = tid + NT * i;
      if (idx < 3200) {
        float4 v = Xb4[idx];
        dst[2*idx]   = pkh2(v.x, v.y);
        dst[2*idx+1] = pkh2(v.z, v.w);
      }
    }
  }
  __syncthreads();
  float sval = 0.f;
  if (tid < 128) {
    #pragma unroll 4
    for (int t = 0; t < T_; ++t)
      sval += h2f(sxh[t * 128 + tid]) * eAw[256 + t];
  }
  float ee = (tid < 128) ? __expf(sval) : 0.f;
  float sm = wsum(ee);
  if (lane == 0 && wv < 2) sred[2 + wv] = sm;
  __syncthreads();
  if (tid < 128) {
    su[tid] = ee * rcpf_(sred[2] + sred[3]);
    sh[tid] = 0.f; sc[tid] = 0.f; shp[tid] = 0; scp[tid] = 0;
  }
  __syncthreads();
  {
    u32* sx32 = (u32*)sxh;
    #pragma unroll
    for (int i = 0; i < 13; ++i) {
      int p = tid + NT * i;
      if (p < 6400) {
        float lo, hi; unph(sx32[p], lo, hi);
        int m = (2 * p) & 127;
        sx32[p] = pkh2(lo * su[m], hi * su[m + 1]);
      }
    }
  }
  __syncthreads();

  u32 wpkH[64], wpkI[64];
  {
    const float4* wr = (const float4*)(eWhh + (size_t)tid * 128);
    #pragma unroll
    for (int i = 0; i < 32; ++i) {
      float4 v = wr[i];
      wpkH[2*i] = pkh2(v.x, v.y); wpkH[2*i+1] = pkh2(v.z, v.w);
    }
    const float4* wi = (const float4*)(eWih + (size_t)tid * 128);
    #pragma unroll
    for (int i = 0; i < 32; ++i) {
      float4 v = wi[i];
      wpkI[2*i] = pkh2(v.x, v.y); wpkI[2*i+1] = pkh2(v.z, v.w);
    }
  }
  float biasg = ebih[tid] + ebhh[tid];

  for (int t = 0; t < T_; ++t) {
    float a0 = biasg, a1 = 0.f, a2 = 0.f, a3 = 0.f;
    const uint4* hr = (const uint4*)(const u32*)shp;
    #pragma unroll
    for (int k = 0; k < 16; ++k) {
      uint4 hv = hr[k];
      a0 = dot2h(wpkH[4*k+0], hv.x, a0);
      a1 = dot2h(wpkH[4*k+1], hv.y, a1);
      a2 = dot2h(wpkH[4*k+2], hv.z, a2);
      a3 = dot2h(wpkH[4*k+3], hv.w, a3);
    }
    const uint4* xr = (const uint4*)((const u32*)sxh + t * 64);
    #pragma unroll
    for (int k = 0; k < 16; ++k) {
      uint4 xv = xr[k];
      a0 = dot2h(wpkI[4*k+0], xv.x, a0);
      a1 = dot2h(wpkI[4*k+1], xv.y, a1);
      a2 = dot2h(wpkI[4*k+2], xv.z, a2);
      a3 = dot2h(wpkI[4*k+3], xv.w, a3);
    }
    sg[tid] = (a0 + a1) + (a2 + a3);
    __syncthreads();
    if (tid < 128) {
      float gi = sigm(sg[tid]);
      float gf = sigm(sg[tid + 128]);
      float gg = tanh_(sg[tid + 256]);
      float go = sigm(sg[tid + 384]);
      float c  = gf * sc[tid] + gi * gg;
      sc[tid]  = c;
      float h  = go * tanh_(c);
      sh[tid]  = h;
      u16 hb = f2h(h);
      shp[tid] = hb; scp[tid] = f2h(c);
      sXe[t * 128 + tid] = hb;
    }
    __syncthreads();
  }

  {
    u32 wtp[64];
    const float4* w4 = (const float4*)(dW1 + (size_t)hh * 384 + 256);
    #pragma unroll
    for (int i = 0; i < 32; ++i) {
      float4 v = w4[i];
      wtp[2*i] = pkh2(v.x, v.y); wtp[2*i+1] = pkh2(v.z, v.w);
    }
    float b1v = db1[hh];
    u16 e1out[25];
    #pragma unroll 1
    for (int i = 0; i < 25; ++i) {
      int t = q4 * 25 + i;
      const uint4* xe4 = (const uint4*)(sXe + t * 128);
      float a0 = 0.f, a1 = 0.f;
      #pragma unroll
      for (int k = 0; k < 16; ++k) {
        uint4 xv = xe4[k];
        a0 = dot2h(wtp[4*k+0], xv.x, a0);
        a1 = dot2h(wtp[4*k+1], xv.y, a1);
        a0 = dot2h(wtp[4*k+2], xv.z, a0);
        a1 = dot2h(wtp[4*k+3], xv.w, a1);
      }
      e1out[i] = f2h(a0 + a1 + b1v);
    }
    __syncthreads();
    #pragma unroll 1
    for (int i = 0; i < 25; ++i)
      sxh[(q4 * 25 + i) * 128 + hh] = e1out[i];
  }

  u32 wpkD[64];
  {
    const float4* wr = (const float4*)(dWhh + (size_t)tid * 128);
    #pragma unroll
    for (int i = 0; i < 32; ++i) {
      float4 v = wr[i];
      wpkD[2*i] = pkh2(v.x, v.y); wpkD[2*i+1] = pkh2(v.z, v.w);
    }
  }
  u32 wtpU[32];
  {
    const float4* wu = (const float4*)(dW1 + (size_t)hh * 384 + q4 * 64);
    #pragma unroll
    for (int i = 0; i < 16; ++i) {
      float4 v = wu[i];
      wtpU[2*i] = pkh2(v.x, v.y); wtpU[2*i+1] = pkh2(v.z, v.w);
    }
  }
  float biasD = dbih[tid] + dbhh[tid];
  float wihj  = dWih[tid];
  float w2a   = dW2[lane];
  float w2b   = dW2[lane + 64];
  float fcbv  = fcb[0];
  float fcwv  = (tid < 128) ? fcW[tid] : 0.f;
  if (tid < 128) { sh[tid] = 0.f; sc[tid] = 0.f; shp[tid] = 0; scp[tid] = 0; }
  __syncthreads();

  for (int step = 0; step < T_; ++step) {
    {
      const u32* base = (q4 < 2) ? (const u32*)shp : (const u32*)scp;
      const uint4* vp = (const uint4*)(base + (q4 & 1) * 32);
      float a0 = 0.f, a1 = 0.f;
      #pragma unroll
      for (int k = 0; k < 8; ++k) {
        uint4 v = vp[k];
        a0 = dot2h(wtpU[4*k+0], v.x, a0);
        a1 = dot2h(wtpU[4*k+1], v.y, a1);
        a0 = dot2h(wtpU[4*k+2], v.z, a0);
        a1 = dot2h(wtpU[4*k+3], v.w, a1);
      }
      spart[q4 * 128 + hh] = a0 + a1;
    }
    __syncthreads();
    {
      float ul = spart[lane] + spart[128 + lane]
               + spart[256 + lane] + spart[384 + lane];
      float uh = spart[64 + lane] + spart[192 + lane]
               + spart[320 + lane] + spart[448 + lane];
      #pragma unroll 1
      for (int i = 0; i < 13; ++i) {
        int t = wv + 8 * i;
        if (t < T_) {
          float v = w2a * ptanh(h2f(sxh[t * 128 + lane]) + ul)
                  + w2b * ptanh(h2f(sxh[t * 128 + 64 + lane]) + uh);
          v = wsum(v);
          if (lane == 0) sscore[t] = v;
        }
      }
    }
    __syncthreads();
    if (wv == 0) {
      float s0 = sscore[lane];
      float E0 = __expf(s0);
      float E1v = (lane < 36) ? __expf(sscore[lane + 64]) : 0.f;
      float s  = wsum(E0 + E1v);
      float iv = rcpf_(s);
      sscore[lane] = E0 * iv;
      if (lane < 36) sscore[lane + 64] = E1v * iv;
    }
    __syncthreads();
    {
      float pc = 0.f;
      #pragma unroll
      for (int i = 0; i < 25; ++i) {
        int t = q4 * 25 + i;
        pc += sscore[t] * h2f(sXe[t * 128 + hh]);
      }
      spart[q4 * 128 + hh] = pc;
    }
    __syncthreads();
    {
      float v = 0.f;
      if (tid < 128) {
        float cx = spart[tid] + spart[tid + 128]
                 + spart[tid + 256] + spart[tid + 384];
        sctx[tid] = cx;
        v = fcwv * cx;
      }
      v = wsum(v);
      if (lane == 0 && wv < 2) sredY[wv] = v;
    }
    __syncthreads();
    {
      float yt = sredY[0] + sredY[1] + fcbv;
      float a0 = biasD + wihj * yt, a1 = 0.f, a2 = 0.f, a3 = 0.f;
      const uint4* hr = (const uint4*)(const u32*)shp;
      #pragma unroll
      for (int k = 0; k < 16; ++k) {
        uint4 hv = hr[k];
        a0 = dot2h(wpkD[4*k+0], hv.x, a0);
        a1 = dot2h(wpkD[4*k+1], hv.y, a1);
        a2 = dot2h(wpkD[4*k+2], hv.z, a2);
        a3 = dot2h(wpkD[4*k+3], hv.w, a3);
      }
      sg[tid] = (a0 + a1) + (a2 + a3);
    }
    __syncthreads();
    if (tid < 128) {
      float gi = sigm(sg[tid]);
      float gf = sigm(sg[tid + 128]);
      float gg = tanh_(sg[tid + 256]);
      float go = sigm(sg[tid + 384]);
      float c  = gf * sc[tid] + gi * gg;
      sc[tid]  = c;
      float d  = go * tanh_(c);
      sh[tid]  = d;
      shp[tid] = f2h(d);
      scp[tid] = f2h(c);
    }
    __syncthreads();
  }

  if (tid < C_) {
    float acc = fcfb[tid];
    const float* w = fcfW + (size_t)tid * 256;
    #pragma unroll 8
    for (int k = 0; k < 128; ++k)
      acc += w[k] * sh[k] + w[128 + k] * sctx[k];
    out[(size_t)b * C_ + tid] = acc;
  }
}

extern "C" void kernel_launch(void* const* d_in, const int* in_sizes, int n_in,
                              void* d_out, int out_size, void* d_ws, size_t ws_size,
                              hipStream_t stream) {
  (void)n_in; (void)out_size;
  const float* X    = (const float*)d_in[0];
  const float* eWih = (const float*)d_in[1];
  const float* eWhh = (const float*)d_in[2];
  const float* ebih = (const float*)d_in[3];
  const float* ebhh = (const float*)d_in[4];
  const float* eAw  = (const float*)d_in[5];
  const float* eAb  = (const float*)d_in[6];
  const float* dW1  = (const float*)d_in[7];
  const float* db1  = (const float*)d_in[8];
  const float* dW2  = (const float*)d_in[9];
  const float* db2  = (const float*)d_in[10];
  const float* dWih = (const float*)d_in[11];
  const float* dWhh = (const float*)d_in[12];
  const float* dbih = (const float*)d_in[13];
  const float* dbhh = (const float*)d_in[14];
  const float* fcW  = (const float*)d_in[15];
  const float* fcb  = (const float*)d_in[16];
  const float* fcfW = (const float*)d_in[17];
  const float* fcfb = (const float*)d_in[18];
  float* out = (float*)d_out;

  const int B = in_sizes[0] / (T_ * 128);
  const size_t needQ = (size_t)B * QS * sizeof(u16);
  if (ws_size >= needQ && (B % BPB) == 0) {
    darnn4<<<dim3(B / BPB), dim3(NT), 0, stream>>>(
        X, eWih, eWhh, ebih, ebhh, eAw, eAb,
        dW1, db1, dW2, db2, dWih, dWhh, dbih, dbhh,
        fcW, fcb, fcfW, fcfb, (u16*)d_ws, out);
  } else {
    darnn_fb<<<dim3(B), dim3(NT), 0, stream>>>(
        X, eWih, eWhh, ebih, ebhh, eAw,
        dW1, db1, dW2, dWih, dWhh, dbih, dbhh,
        fcW, fcb, fcfW, fcfb, out);
  }
}